// Round 4
// baseline (4835.899 us; speedup 1.0000x reference)
//
#include <hip/hip_runtime.h>
#include <stdint.h>

typedef unsigned short u16;
typedef __attribute__((ext_vector_type(8))) short short8;
typedef __attribute__((ext_vector_type(4))) float f32x4;

#define MFMA __builtin_amdgcn_mfma_f32_16x16x32_bf16

__device__ __forceinline__ u16 f2bf(float f) {
  union { float f; uint32_t u; } v; v.f = f;
  return (u16)((v.u + 0x7FFFu + ((v.u >> 16) & 1u)) >> 16);
}

// ws layout (bytes)
#define WS_H    0          // u16 H[64][2][8][9][64][8]  fragment-major (9,437,184 B)
#define WS_P1   9437184    // f32 P1[128][128]
#define WS_Q1   9502720    // f32 q1[128]
#define WS_Q2   9503232    // f32 q2[128]
#define WS_M1P  9503744    // u64 m1p[64][4096]   (TRANSPOSED: [kt][row])
#define WS_M2P  11600896   // u64 m2p[64][4096]
#define WS_RS1  13698048   // f32 rs1[4096]
#define WS_RS2  13714432   // f32 rs2[4096]

// ---------------- kernel M: pack masks into bits (transposed) + row sums ----------------
__global__ __launch_bounds__(256) void kmask(const int* __restrict__ sp,
                                             unsigned long long* __restrict__ m1p,
                                             unsigned long long* __restrict__ m2p,
                                             float* __restrict__ rs1, float* __restrict__ rs2) {
  int wave = threadIdx.x >> 6, lane = threadIdx.x & 63;
  int i = blockIdx.x * 4 + wave;
  const int* rowp = sp + (size_t)i * 4096;
  int c1 = 0, c2 = 0;
  for (int w = 0; w < 64; ++w) {
    int v = rowp[w * 64 + lane];
    unsigned long long b1 = __ballot(v <= 1);
    unsigned long long b2 = __ballot(v == 2);
    if (lane == 0) {
      m1p[(size_t)w * 4096 + i] = b1;   // [kt][row]
      m2p[(size_t)w * 4096 + i] = b2;
      c1 += __popcll(b1);
      c2 += __popcll(b2);
    }
  }
  if (lane == 0) { rs1[i] = (float)c1; rs2[i] = (float)c2; }
}

// ---------------- kernel P: P1 = W1 @ Wb1, q1 = b1@Wb1, q2 = b2@Wb2 ----------------
__global__ __launch_bounds__(256) void kprep(const float* __restrict__ W1, const float* __restrict__ Wb,
                                             const float* __restrict__ b1, const float* __restrict__ b2,
                                             float* __restrict__ P1, float* __restrict__ q1,
                                             float* __restrict__ q2) {
  int idx = blockIdx.x * 256 + threadIdx.x;   // 0..16383
  int a = idx >> 7, c = idx & 127;
  float acc = 0.f;
  for (int k = 0; k < 128; ++k) acc += W1[a * 128 + k] * Wb[k * 128 + c];
  P1[idx] = acc;
  if (idx < 128) {
    float s1 = 0.f, s2 = 0.f;
    for (int k = 0; k < 128; ++k) s1 += b1[k] * Wb[k * 128 + idx];
    for (int k = 0; k < 16; ++k)  s2 += b2[k] * Wb[(128 + k) * 128 + idx];
    q1[idx] = s1; q2[idx] = s2;
  }
}

// ---------------- kernel A': u1 = x@P1, h2 = x@W2 -> fragment-major H ----------------
// H element (kt,kf,b,fn,lane=lg*16+lr,r) = u1h2[b][kt*64+kf*32+lg*8+r][fn*16+lr]
__global__ __launch_bounds__(256, 2) void kproj(const float* __restrict__ x,
                                                const float* __restrict__ P1f,
                                                const float* __restrict__ W2,
                                                u16* __restrict__ H) {
  __shared__ u16 wsb[16 * 144 * 8];       // B operand blocked [jb][n][r]
  __shared__ u16 uni[64 * 146];           // union: xs[64][136] then hs[64][146]
  u16* xs = uni;
  u16* hs = uni;
  const int tid = threadIdx.x;
  const int r0 = blockIdx.x * 64;         // global row in [0,32768)

  // stage B operand: [P1 | W2] -> blocked bf16
  for (int i = 0; i < 72; ++i) {
    int e = i * 256 + tid;                // (k, nn) row-major, 128x144
    int k = e / 144, nn = e % 144;
    float v = (nn < 128) ? P1f[k * 128 + nn] : W2[k * 16 + (nn - 128)];
    wsb[((k >> 3) * 144 + nn) * 8 + (k & 7)] = f2bf(v);
  }
  // stage x rows -> xs[64][136] bf16
  {
    const float* xp = x + ((size_t)(r0 + (tid >> 2))) * 128 + (tid & 3) * 32;
    u16* xd = xs + (tid >> 2) * 136 + (tid & 3) * 32;
#pragma unroll
    for (int i = 0; i < 4; ++i) {
      f32x4 a = ((const f32x4*)xp)[i * 2];
      f32x4 b = ((const f32x4*)xp)[i * 2 + 1];
      short8 pk;
      pk[0] = (short)f2bf(a[0]); pk[1] = (short)f2bf(a[1]);
      pk[2] = (short)f2bf(a[2]); pk[3] = (short)f2bf(a[3]);
      pk[4] = (short)f2bf(b[0]); pk[5] = (short)f2bf(b[1]);
      pk[6] = (short)f2bf(b[2]); pk[7] = (short)f2bf(b[3]);
      *(short8*)(xd + i * 8) = pk;
    }
  }
  __syncthreads();

  const int w = tid >> 6, l = tid & 63, lr = l & 15, lg = l >> 4;
  f32x4 acc[9];
  f32x4 zz = {0.f, 0.f, 0.f, 0.f};
#pragma unroll
  for (int fn = 0; fn < 9; ++fn) acc[fn] = zz;
#pragma unroll
  for (int kf = 0; kf < 4; ++kf) {
    short8 af = *(const short8*)(xs + (w * 16 + lr) * 136 + kf * 32 + lg * 8);
#pragma unroll
    for (int fn = 0; fn < 9; ++fn) {
      short8 bf = *(const short8*)(wsb + (((kf * 4 + lg) * 144) + fn * 16 + lr) * 8);
      acc[fn] = MFMA(af, bf, acc[fn], 0, 0, 0);
    }
  }
  __syncthreads();
  // write hs[64][146] bf16
#pragma unroll
  for (int fn = 0; fn < 9; ++fn)
#pragma unroll
    for (int g = 0; g < 4; ++g)
      hs[(w * 16 + lg * 4 + g) * 146 + fn * 16 + lr] = f2bf(acc[fn][g]);
  __syncthreads();
  // fragment-major coalesced write to H
  {
    const int b = r0 >> 12;
    const int kt = (r0 & 4095) >> 6;
    for (int i = 0; i < 5; ++i) {
      int e = i * 256 + tid;
      if (e < 1152) {
        int jbl = e / 144, n = e % 144;
        union { u16 s[8]; uint4 v; } pk;
#pragma unroll
        for (int r = 0; r < 8; ++r) pk.s[r] = hs[(jbl * 8 + r) * 146 + n];
        int kf = jbl >> 2, lgw = jbl & 3, fn = n >> 4, lrw = n & 15;
        size_t di = ((((size_t)kt * 2 + kf) * 8 + b) * 9 + fn) * 512 + (lgw * 16 + lrw) * 8;
        *(uint4*)(H + di) = pk.v;
      }
    }
  }
}

// expand 8 mask bits (byte lgsh/8 of a 32-bit half-word) -> 8 bf16 {0,1} packed as short8
__device__ __forceinline__ short8 expand_byte(uint32_t wd, int lgsh) {
  uint32_t b = (wd >> lgsh) & 0xFFu;     // v_bfe
  uint32_t t = b * 0x8001u;              // low half = b, bits16.. = b>>1
  union { uint32_t u[4]; short8 s; } r;
  r.u[0] = (t & 0x00010001u) * 0x3F80u;  // bits 0,1
  r.u[1] = (t & 0x00040004u) * 0x0FE0u;  // bits 2,3
  r.u[2] = (t & 0x00100010u) * 0x03F8u;  // bits 4,5
  r.u[3] = (t & 0x00400040u) * 0x00FEu;  // bits 6,7
  return r.s;
}

// ---------------- kernel B1: out = m1@u1 + (m2@h2)@Wb2 + rs1*q1 + rs2*q2 + bb ----------------
// grid 256 (b = bid&7 XCD-pinned, panel = bid>>3), 1024 threads = 16 waves, NO main-loop barriers.
// wave (r = w>>2, c = w&3): m1 fm-tiles {2r,2r+1} x fn {2c,2c+1}; m2 (fm2 = 2r+(c&1), kf2 = c>>1).
__global__ __launch_bounds__(1024, 4) void kb1(const u16* __restrict__ H,
                                               const uint2* __restrict__ M1,
                                               const uint32_t* __restrict__ M2w,
                                               const float* __restrict__ rs1, const float* __restrict__ rs2,
                                               const float* __restrict__ q1, const float* __restrict__ q2,
                                               const float* __restrict__ Wb, const float* __restrict__ bb,
                                               float* __restrict__ out) {
  __shared__ float f2pf[2][128][16];       // m2@h2 kf-partials (16 KB)
  __shared__ u16 f2s[128 * 40];            // f2 bf16, K padded to 32 (10 KB)
  __shared__ u16 wb2s[4096];               // Wb2 padded to K=32, fragment-blocked (8 KB)

  const int tid = threadIdx.x;
  const int bid = blockIdx.x;
  const int b = bid & 7;
  const int panel = bid >> 3;
  const int i0 = panel * 128;

  // stage Wb2 once (rows 128..143 of Wb, zero-padded to K=32)
#pragma unroll
  for (int i = 0; i < 4; ++i) {
    int e = i * 1024 + tid;                // (jb*128+n)*8 + r
    int r_ = e & 7, nn = (e >> 3) & 127, jb = e >> 10;
    int k = jb * 8 + r_;
    float v = (k < 16) ? Wb[(128 + k) * 128 + nn] : 0.f;
    wb2s[e] = f2bf(v);
  }

  const int w = tid >> 6, l = tid & 63, lr = l & 15, lg = l >> 4;
  const int r = w >> 2, c = w & 3;
  const int fm2 = r * 2 + (c & 1), kf2 = c >> 1;
  const int lgsh = lg * 8;

  // fragment pointers: frag(kt,kf,fn) base = (((kt*2+kf)*8 + b)*9 + fn)*512
  const u16* fp[4];                        // [kf*2+fj] for m1
#pragma unroll
  for (int kf = 0; kf < 2; ++kf)
#pragma unroll
    for (int fj = 0; fj < 2; ++fj)
      fp[kf * 2 + fj] = H + (((size_t)kf * 8 + b) * 9 + (2 * c + fj)) * 512 + l * 8;
  const u16* fpm = H + (((size_t)kf2 * 8 + b) * 9 + 8) * 512 + l * 8;

  // mask pointers (transposed layout M[kt*4096 + row])
  const uint2* mp1a = M1 + (i0 + (r * 2 + 0) * 16 + lr);
  const uint2* mp1b = M1 + (i0 + (r * 2 + 1) * 16 + lr);
  const uint32_t* mp2 = M2w + (size_t)(i0 + fm2 * 16 + lr) * 2 + kf2;

  f32x4 zz = {0.f, 0.f, 0.f, 0.f};
  f32x4 acc[2][2];
  f32x4 acc2 = zz;
#pragma unroll
  for (int i = 0; i < 2; ++i) { acc[i][0] = zz; acc[i][1] = zz; }

  // register ping-pong prefetch
  short8 bfr[2][4];
  uint2 cm1[2][2];
  uint32_t cm2[2];
#pragma unroll
  for (int j = 0; j < 4; ++j) bfr[0][j] = *(const short8*)(fp[j]);
  cm1[0][0] = mp1a[0]; cm1[0][1] = mp1b[0]; cm2[0] = mp2[0];

#pragma unroll 2
  for (int kt = 0; kt < 64; ++kt) {
    const int cu = kt & 1, nx = cu ^ 1;
    // issue next-tile loads first (hide under current MFMAs)
    if (kt < 63) {
      const size_t ho = (size_t)(kt + 1) * 73728;
#pragma unroll
      for (int j = 0; j < 4; ++j) bfr[nx][j] = *(const short8*)(fp[j] + ho);
      cm1[nx][0] = mp1a[(size_t)(kt + 1) * 4096];
      cm1[nx][1] = mp1b[(size_t)(kt + 1) * 4096];
      cm2[nx]    = mp2[(size_t)(kt + 1) * 8192];
    }
    short8 bm2 = *(const short8*)(fpm + (size_t)kt * 73728);

    // expand current masks -> A fragments (registers only)
    short8 a1[2][2], a2v;
    a1[0][0] = expand_byte(cm1[cu][0].x, lgsh);
    a1[0][1] = expand_byte(cm1[cu][0].y, lgsh);
    a1[1][0] = expand_byte(cm1[cu][1].x, lgsh);
    a1[1][1] = expand_byte(cm1[cu][1].y, lgsh);
    a2v = expand_byte(cm2[cu], lgsh);

#pragma unroll
    for (int kf = 0; kf < 2; ++kf)
#pragma unroll
      for (int i = 0; i < 2; ++i) {
        acc[i][0] = MFMA(a1[i][kf], bfr[cu][kf * 2 + 0], acc[i][0], 0, 0, 0);
        acc[i][1] = MFMA(a1[i][kf], bfr[cu][kf * 2 + 1], acc[i][1], 0, 0, 0);
      }
    acc2 = MFMA(a2v, bm2, acc2, 0, 0, 0);
  }

  // epilogue: combine acc2 kf-partials -> f2 bf16 tile, one barrier pair
#pragma unroll
  for (int g = 0; g < 4; ++g)
    f2pf[kf2][fm2 * 16 + lg * 4 + g][lr] = acc2[g];
  // zero-pad f2s cols 16..31
#pragma unroll
  for (int j = 0; j < 2; ++j) {
    int e = tid * 2 + j;
    f2s[(e >> 4) * 40 + 16 + (e & 15)] = 0;
  }
  __syncthreads();
#pragma unroll
  for (int j = 0; j < 2; ++j) {
    int e = tid * 2 + j;
    int row = e >> 4, col = e & 15;
    f2s[row * 40 + col] = f2bf(f2pf[0][row][col] + f2pf[1][row][col]);
  }
  __syncthreads();

  // epilogue MFMA: acc[i][fj] += f2frag(fm-tile 2r+i) x Wb2frag(fn)
#pragma unroll
  for (int i = 0; i < 2; ++i) {
    short8 af = *(const short8*)(f2s + ((r * 2 + i) * 16 + lr) * 40 + lg * 8);
#pragma unroll
    for (int fj = 0; fj < 2; ++fj) {
      int fn = 2 * c + fj;
      short8 bf = *(const short8*)(wb2s + ((lg * 128) + fn * 16 + lr) * 8);
      acc[i][fj] = MFMA(af, bf, acc[i][fj], 0, 0, 0);
    }
  }

  // final: + rs1*q1 + rs2*q2 + bb, store f32
  float q1v[2], q2v[2], bbv[2];
#pragma unroll
  for (int fj = 0; fj < 2; ++fj) {
    int col = (2 * c + fj) * 16 + lr;
    q1v[fj] = q1[col]; q2v[fj] = q2[col]; bbv[fj] = bb[col];
  }
#pragma unroll
  for (int i = 0; i < 2; ++i)
#pragma unroll
    for (int g = 0; g < 4; ++g) {
      int row = (r * 2 + i) * 16 + lg * 4 + g;
      float r1 = rs1[i0 + row], r2 = rs2[i0 + row];
      size_t obase = ((size_t)b * 4096 + i0 + row) * 128;
#pragma unroll
      for (int fj = 0; fj < 2; ++fj) {
        int col = (2 * c + fj) * 16 + lr;
        out[obase + col] = acc[i][fj][g] + r1 * q1v[fj] + r2 * q2v[fj] + bbv[fj];
      }
    }
}

extern "C" void kernel_launch(void* const* d_in, const int* in_sizes, int n_in,
                              void* d_out, int out_size, void* d_ws, size_t ws_size,
                              hipStream_t stream) {
  const float* x  = (const float*)d_in[0];
  const int*   sp = (const int*)d_in[1];
  const float* W1 = (const float*)d_in[2];
  const float* b1 = (const float*)d_in[3];
  const float* W2 = (const float*)d_in[4];
  const float* b2 = (const float*)d_in[5];
  const float* Wb = (const float*)d_in[6];
  const float* bb = (const float*)d_in[7];
  float* out = (float*)d_out;
  char* ws = (char*)d_ws;

  u16* H = (u16*)(ws + WS_H);
  float* P1 = (float*)(ws + WS_P1);
  float* q1 = (float*)(ws + WS_Q1);
  float* q2 = (float*)(ws + WS_Q2);
  unsigned long long* m1p = (unsigned long long*)(ws + WS_M1P);
  unsigned long long* m2p = (unsigned long long*)(ws + WS_M2P);
  float* rs1 = (float*)(ws + WS_RS1);
  float* rs2 = (float*)(ws + WS_RS2);

  kmask<<<1024, 256, 0, stream>>>(sp, m1p, m2p, rs1, rs2);
  kprep<<<64, 256, 0, stream>>>(W1, Wb, b1, b2, P1, q1, q2);
  kproj<<<512, 256, 0, stream>>>(x, P1, W2, H);
  kb1<<<256, 1024, 0, stream>>>(H, (const uint2*)m1p, (const uint32_t*)m2p,
                                rs1, rs2, q1, q2, Wb, bb, out);
}

// Round 5
// 1873.446 us; speedup vs baseline: 2.5813x; 2.5813x over previous
//
#include <hip/hip_runtime.h>
#include <stdint.h>

typedef unsigned short u16;
typedef __attribute__((ext_vector_type(8))) short short8;
typedef __attribute__((ext_vector_type(4))) float f32x4;

#define MFMA __builtin_amdgcn_mfma_f32_16x16x32_bf16

__device__ __forceinline__ u16 f2bf(float f) {
  union { float f; uint32_t u; } v; v.f = f;
  return (u16)((v.u + 0x7FFFu + ((v.u >> 16) & 1u)) >> 16);
}

// ws layout (bytes)
#define WS_H    0          // u16 H[64][2][8][9][64][8]  fragment-major (9,437,184 B)
#define WS_P1   9437184    // f32 P1[128][128]
#define WS_Q1   9502720    // f32 q1[128]
#define WS_Q2   9503232    // f32 q2[128]
#define WS_M1P  9503744    // u64 m1p[64][4096]   (TRANSPOSED: [kt][row])
#define WS_M2P  11600896   // u64 m2p[64][4096]
#define WS_RS1  13698048   // f32 rs1[4096]
#define WS_RS2  13714432   // f32 rs2[4096]

// ---------------- kernel M: pack masks into bits (transposed) + row sums ----------------
__global__ __launch_bounds__(256) void kmask(const int* __restrict__ sp,
                                             unsigned long long* __restrict__ m1p,
                                             unsigned long long* __restrict__ m2p,
                                             float* __restrict__ rs1, float* __restrict__ rs2) {
  int wave = threadIdx.x >> 6, lane = threadIdx.x & 63;
  int i = blockIdx.x * 4 + wave;
  const int* rowp = sp + (size_t)i * 4096;
  int c1 = 0, c2 = 0;
  for (int w = 0; w < 64; ++w) {
    int v = rowp[w * 64 + lane];
    unsigned long long b1 = __ballot(v <= 1);
    unsigned long long b2 = __ballot(v == 2);
    if (lane == 0) {
      m1p[(size_t)w * 4096 + i] = b1;   // [kt][row]
      m2p[(size_t)w * 4096 + i] = b2;
      c1 += __popcll(b1);
      c2 += __popcll(b2);
    }
  }
  if (lane == 0) { rs1[i] = (float)c1; rs2[i] = (float)c2; }
}

// ---------------- kernel P: P1 = W1 @ Wb1, q1 = b1@Wb1, q2 = b2@Wb2 ----------------
__global__ __launch_bounds__(256) void kprep(const float* __restrict__ W1, const float* __restrict__ Wb,
                                             const float* __restrict__ b1, const float* __restrict__ b2,
                                             float* __restrict__ P1, float* __restrict__ q1,
                                             float* __restrict__ q2) {
  int idx = blockIdx.x * 256 + threadIdx.x;   // 0..16383
  int a = idx >> 7, c = idx & 127;
  float acc = 0.f;
  for (int k = 0; k < 128; ++k) acc += W1[a * 128 + k] * Wb[k * 128 + c];
  P1[idx] = acc;
  if (idx < 128) {
    float s1 = 0.f, s2 = 0.f;
    for (int k = 0; k < 128; ++k) s1 += b1[k] * Wb[k * 128 + idx];
    for (int k = 0; k < 16; ++k)  s2 += b2[k] * Wb[(128 + k) * 128 + idx];
    q1[idx] = s1; q2[idx] = s2;
  }
}

// ---------------- kernel A': u1 = x@P1, h2 = x@W2 -> fragment-major H ----------------
// H element (kt,kf,b,fn,lane=lg*16+lr,r) = u1h2[b][kt*64+kf*32+lg*8+r][fn*16+lr]
__global__ __launch_bounds__(256, 2) void kproj(const float* __restrict__ x,
                                                const float* __restrict__ P1f,
                                                const float* __restrict__ W2,
                                                u16* __restrict__ H) {
  __shared__ u16 wsb[16 * 144 * 8];       // B operand blocked [jb][n][r]
  __shared__ u16 uni[64 * 146];           // union: xs[64][136] then hs[64][146]
  u16* xs = uni;
  u16* hs = uni;
  const int tid = threadIdx.x;
  const int r0 = blockIdx.x * 64;         // global row in [0,32768)

  // stage B operand: [P1 | W2] -> blocked bf16
  for (int i = 0; i < 72; ++i) {
    int e = i * 256 + tid;                // (k, nn) row-major, 128x144
    int k = e / 144, nn = e % 144;
    float v = (nn < 128) ? P1f[k * 128 + nn] : W2[k * 16 + (nn - 128)];
    wsb[((k >> 3) * 144 + nn) * 8 + (k & 7)] = f2bf(v);
  }
  // stage x rows -> xs[64][136] bf16
  {
    const float* xp = x + ((size_t)(r0 + (tid >> 2))) * 128 + (tid & 3) * 32;
    u16* xd = xs + (tid >> 2) * 136 + (tid & 3) * 32;
#pragma unroll
    for (int i = 0; i < 4; ++i) {
      f32x4 a = ((const f32x4*)xp)[i * 2];
      f32x4 b = ((const f32x4*)xp)[i * 2 + 1];
      short8 pk;
      pk[0] = (short)f2bf(a[0]); pk[1] = (short)f2bf(a[1]);
      pk[2] = (short)f2bf(a[2]); pk[3] = (short)f2bf(a[3]);
      pk[4] = (short)f2bf(b[0]); pk[5] = (short)f2bf(b[1]);
      pk[6] = (short)f2bf(b[2]); pk[7] = (short)f2bf(b[3]);
      *(short8*)(xd + i * 8) = pk;
    }
  }
  __syncthreads();

  const int w = tid >> 6, l = tid & 63, lr = l & 15, lg = l >> 4;
  f32x4 acc[9];
  f32x4 zz = {0.f, 0.f, 0.f, 0.f};
#pragma unroll
  for (int fn = 0; fn < 9; ++fn) acc[fn] = zz;
#pragma unroll
  for (int kf = 0; kf < 4; ++kf) {
    short8 af = *(const short8*)(xs + (w * 16 + lr) * 136 + kf * 32 + lg * 8);
#pragma unroll
    for (int fn = 0; fn < 9; ++fn) {
      short8 bf = *(const short8*)(wsb + (((kf * 4 + lg) * 144) + fn * 16 + lr) * 8);
      acc[fn] = MFMA(af, bf, acc[fn], 0, 0, 0);
    }
  }
  __syncthreads();
  // write hs[64][146] bf16
#pragma unroll
  for (int fn = 0; fn < 9; ++fn)
#pragma unroll
    for (int g = 0; g < 4; ++g)
      hs[(w * 16 + lg * 4 + g) * 146 + fn * 16 + lr] = f2bf(acc[fn][g]);
  __syncthreads();
  // fragment-major coalesced write to H
  {
    const int b = r0 >> 12;
    const int kt = (r0 & 4095) >> 6;
    for (int i = 0; i < 5; ++i) {
      int e = i * 256 + tid;
      if (e < 1152) {
        int jbl = e / 144, n = e % 144;
        union { u16 s[8]; uint4 v; } pk;
#pragma unroll
        for (int r = 0; r < 8; ++r) pk.s[r] = hs[(jbl * 8 + r) * 146 + n];
        int kf = jbl >> 2, lgw = jbl & 3, fn = n >> 4, lrw = n & 15;
        size_t di = ((((size_t)kt * 2 + kf) * 8 + b) * 9 + fn) * 512 + (lgw * 16 + lrw) * 8;
        *(uint4*)(H + di) = pk.v;
      }
    }
  }
}

// expand 8 mask bits (byte lgsh/8 of a 32-bit half-word) -> 8 bf16 {0,1} packed as short8
__device__ __forceinline__ short8 expand_byte(uint32_t wd, int lgsh) {
  uint32_t b = (wd >> lgsh) & 0xFFu;     // v_bfe
  uint32_t t = b * 0x8001u;              // low half = b, bits16.. = b>>1
  union { uint32_t u[4]; short8 s; } r;
  r.u[0] = (t & 0x00010001u) * 0x3F80u;  // bits 0,1
  r.u[1] = (t & 0x00040004u) * 0x0FE0u;  // bits 2,3
  r.u[2] = (t & 0x00100010u) * 0x03F8u;  // bits 4,5
  r.u[3] = (t & 0x00400040u) * 0x00FEu;  // bits 6,7
  return r.s;
}

// ---------------- kernel B1: out = m1@u1 + (m2@h2)@Wb2 + rs1*q1 + rs2*q2 + bb ----------------
// grid 256 (b = bid&7 XCD-pinned -> 1 block/CU), 512 threads = 8 waves, NO main-loop barriers/LDS.
// wave w owns output col-tile fn=w (acc[fm=0..7]) + m2 fm=w (acc2, both kf in-register).
__global__ __launch_bounds__(512, 2) void kb1(const u16* __restrict__ H,
                                              const uint2* __restrict__ M1,
                                              const uint2* __restrict__ M2,
                                              const float* __restrict__ rs1, const float* __restrict__ rs2,
                                              const float* __restrict__ q1, const float* __restrict__ q2,
                                              const float* __restrict__ Wb, const float* __restrict__ bb,
                                              float* __restrict__ out) {
  __shared__ u16 f2s[128 * 40];            // f2 bf16, K padded to 32 (10 KB)
  __shared__ u16 wb2s[4096];               // Wb2 padded to K=32, fragment-blocked (8 KB)

  const int tid = threadIdx.x;
  const int bid = blockIdx.x;
  const int b = bid & 7;
  const int i0 = (bid >> 3) * 128;

  // stage Wb2 once (rows 128..143 of Wb, zero-padded to K=32)
#pragma unroll
  for (int i = 0; i < 8; ++i) {
    int e = i * 512 + tid;                // (jb*128+n)*8 + r
    int r_ = e & 7, nn = (e >> 3) & 127, jb = e >> 10;
    int k = jb * 8 + r_;
    wb2s[e] = f2bf((k < 16) ? Wb[(128 + k) * 128 + nn] : 0.f);
  }

  const int w = tid >> 6, l = tid & 63, lr = l & 15, lg = l >> 4;
  const int lgsh = lg * 8;

  // B-fragment pointers: frag(kt,kf,fn) base = (((kt*2+kf)*8 + b)*9 + fn)*512
  const u16* fb0 = H + (((size_t)0 * 8 + b) * 9 + w) * 512 + l * 8;   // m1, kf=0
  const u16* fb1 = fb0 + 36864;                                       // m1, kf=1
  const u16* fm0 = H + (((size_t)0 * 8 + b) * 9 + 8) * 512 + l * 8;   // m2, kf=0
  const u16* fm1 = fm0 + 36864;                                       // m2, kf=1
  // mask pointers (transposed layout M[kt*4096 + row])
  const uint2* mp1 = M1 + i0 + lr;
  const uint2* mp2 = M2 + i0 + w * 16 + lr;

  f32x4 zz = {0.f, 0.f, 0.f, 0.f};
  f32x4 acc[8];
  f32x4 acc2 = zz;
#pragma unroll
  for (int fm = 0; fm < 8; ++fm) acc[fm] = zz;

  // register ping-pong state (static-indexed under unroll-2)
  short8 bf[2][2], bm[2][2];
  uint2 cm1[2][8], cm2[2];
  bf[0][0] = *(const short8*)fb0; bf[0][1] = *(const short8*)fb1;
  bm[0][0] = *(const short8*)fm0; bm[0][1] = *(const short8*)fm1;
#pragma unroll
  for (int fm = 0; fm < 8; ++fm) cm1[0][fm] = mp1[fm * 16];
  cm2[0] = mp2[0];

#pragma unroll 2
  for (int kt = 0; kt < 64; ++kt) {
    const int cu = kt & 1, nx = cu ^ 1;
    if (kt < 63) {
      const size_t ho = (size_t)(kt + 1) * 73728;
      bf[nx][0] = *(const short8*)(fb0 + ho);
      bf[nx][1] = *(const short8*)(fb1 + ho);
      bm[nx][0] = *(const short8*)(fm0 + ho);
      bm[nx][1] = *(const short8*)(fm1 + ho);
      const size_t mo = (size_t)(kt + 1) * 4096;
#pragma unroll
      for (int fm = 0; fm < 8; ++fm) cm1[nx][fm] = mp1[mo + fm * 16];
      cm2[nx] = mp2[mo];
    }
#pragma unroll
    for (int fm = 0; fm < 8; ++fm) {
      short8 aA = expand_byte(cm1[cu][fm].x, lgsh);
      short8 aB = expand_byte(cm1[cu][fm].y, lgsh);
      acc[fm] = MFMA(aA, bf[cu][0], acc[fm], 0, 0, 0);
      acc[fm] = MFMA(aB, bf[cu][1], acc[fm], 0, 0, 0);
    }
    acc2 = MFMA(expand_byte(cm2[cu].x, lgsh), bm[cu][0], acc2, 0, 0, 0);
    acc2 = MFMA(expand_byte(cm2[cu].y, lgsh), bm[cu][1], acc2, 0, 0, 0);
  }

  // epilogue: f2 (= m2@h2) -> LDS bf16 tile (K padded to 32, stride 40), one barrier
#pragma unroll
  for (int j = 0; j < 4; ++j) {           // zero-pad cols 16..31 (128 rows x 16)
    int e = tid * 4 + j;
    f2s[(e >> 4) * 40 + 16 + (e & 15)] = 0;
  }
#pragma unroll
  for (int g = 0; g < 4; ++g)
    f2s[(w * 16 + lg * 4 + g) * 40 + lr] = f2bf(acc2[g]);
  __syncthreads();

  // epilogue MFMA: acc[fm] += f2frag(fm) x Wb2frag(fn=w)
  short8 bwb = *(const short8*)(wb2s + ((lg * 128) + w * 16 + lr) * 8);
#pragma unroll
  for (int fm = 0; fm < 8; ++fm) {
    short8 af = *(const short8*)(f2s + (fm * 16 + lr) * 40 + lg * 8);
    acc[fm] = MFMA(af, bwb, acc[fm], 0, 0, 0);
  }

  // final: + rs1*q1 + rs2*q2 + bb, store f32
  const int col = w * 16 + lr;
  const float q1v = q1[col], q2v = q2[col], bbv = bb[col];
#pragma unroll
  for (int fm = 0; fm < 8; ++fm)
#pragma unroll
    for (int g = 0; g < 4; ++g) {
      int row = fm * 16 + lg * 4 + g;
      float r1 = rs1[i0 + row], r2 = rs2[i0 + row];
      out[((size_t)b * 4096 + i0 + row) * 128 + col] = acc[fm][g] + r1 * q1v + r2 * q2v + bbv;
    }
}

extern "C" void kernel_launch(void* const* d_in, const int* in_sizes, int n_in,
                              void* d_out, int out_size, void* d_ws, size_t ws_size,
                              hipStream_t stream) {
  const float* x  = (const float*)d_in[0];
  const int*   sp = (const int*)d_in[1];
  const float* W1 = (const float*)d_in[2];
  const float* b1 = (const float*)d_in[3];
  const float* W2 = (const float*)d_in[4];
  const float* b2 = (const float*)d_in[5];
  const float* Wb = (const float*)d_in[6];
  const float* bb = (const float*)d_in[7];
  float* out = (float*)d_out;
  char* ws = (char*)d_ws;

  u16* H = (u16*)(ws + WS_H);
  float* P1 = (float*)(ws + WS_P1);
  float* q1 = (float*)(ws + WS_Q1);
  float* q2 = (float*)(ws + WS_Q2);
  unsigned long long* m1p = (unsigned long long*)(ws + WS_M1P);
  unsigned long long* m2p = (unsigned long long*)(ws + WS_M2P);
  float* rs1 = (float*)(ws + WS_RS1);
  float* rs2 = (float*)(ws + WS_RS2);

  kmask<<<1024, 256, 0, stream>>>(sp, m1p, m2p, rs1, rs2);
  kprep<<<64, 256, 0, stream>>>(W1, Wb, b1, b2, P1, q1, q2);
  kproj<<<512, 256, 0, stream>>>(x, P1, W2, H);
  kb1<<<256, 512, 0, stream>>>(H, (const uint2*)m1p, (const uint2*)m2p,
                               rs1, rs2, q1, q2, Wb, bb, out);
}

// Round 6
// 125.091 us; speedup vs baseline: 38.6592x; 14.9767x over previous
//
#include <hip/hip_runtime.h>
#include <stdint.h>

typedef unsigned short u16;
typedef __attribute__((ext_vector_type(8))) short short8;
typedef __attribute__((ext_vector_type(4))) float f32x4;

#define MFMA __builtin_amdgcn_mfma_f32_16x16x32_bf16

__device__ __forceinline__ u16 f2bf(float f) {
  union { float f; uint32_t u; } v; v.f = f;
  return (u16)((v.u + 0x7FFFu + ((v.u >> 16) & 1u)) >> 16);
}

// ws layout (bytes)
#define WS_H    0          // u16 H[64][2][8][9][64][8]  fragment-major (9,437,184 B)
#define WS_P1   9437184    // f32 P1[128][128]
#define WS_Q1   9502720    // f32 q1[128]
#define WS_Q2   9503232    // f32 q2[128]
#define WS_M1P  9503744    // u64 m1p[64][4096]   (TRANSPOSED: [kt][row])
#define WS_M2P  11600896   // u64 m2p[64][4096]
#define WS_RS1  13698048   // f32 rs1[4096]
#define WS_RS2  13714432   // f32 rs2[4096]

// ---------------- kernel M: pack masks into bits (transposed) + row sums ----------------
__global__ __launch_bounds__(256) void kmask(const int* __restrict__ sp,
                                             unsigned long long* __restrict__ m1p,
                                             unsigned long long* __restrict__ m2p,
                                             float* __restrict__ rs1, float* __restrict__ rs2) {
  int wave = threadIdx.x >> 6, lane = threadIdx.x & 63;
  int i = blockIdx.x * 4 + wave;
  const int* rowp = sp + (size_t)i * 4096;
  int c1 = 0, c2 = 0;
  for (int w = 0; w < 64; ++w) {
    int v = rowp[w * 64 + lane];
    unsigned long long b1 = __ballot(v <= 1);
    unsigned long long b2 = __ballot(v == 2);
    if (lane == 0) {
      m1p[(size_t)w * 4096 + i] = b1;   // [kt][row]
      m2p[(size_t)w * 4096 + i] = b2;
      c1 += __popcll(b1);
      c2 += __popcll(b2);
    }
  }
  if (lane == 0) { rs1[i] = (float)c1; rs2[i] = (float)c2; }
}

// ---------------- kernel P: P1 = W1 @ Wb1, q1 = b1@Wb1, q2 = b2@Wb2 ----------------
__global__ __launch_bounds__(256) void kprep(const float* __restrict__ W1, const float* __restrict__ Wb,
                                             const float* __restrict__ b1, const float* __restrict__ b2,
                                             float* __restrict__ P1, float* __restrict__ q1,
                                             float* __restrict__ q2) {
  int idx = blockIdx.x * 256 + threadIdx.x;   // 0..16383
  int a = idx >> 7, c = idx & 127;
  float acc = 0.f;
  for (int k = 0; k < 128; ++k) acc += W1[a * 128 + k] * Wb[k * 128 + c];
  P1[idx] = acc;
  if (idx < 128) {
    float s1 = 0.f, s2 = 0.f;
    for (int k = 0; k < 128; ++k) s1 += b1[k] * Wb[k * 128 + idx];
    for (int k = 0; k < 16; ++k)  s2 += b2[k] * Wb[(128 + k) * 128 + idx];
    q1[idx] = s1; q2[idx] = s2;
  }
}

// ---------------- kernel A': u1 = x@P1, h2 = x@W2 -> fragment-major H ----------------
// H element (kt,kf,b,fn,lane=lg*16+lr,r) = u1h2[b][kt*64+kf*32+lg*8+r][fn*16+lr]
__global__ __launch_bounds__(256, 2) void kproj(const float* __restrict__ x,
                                                const float* __restrict__ P1f,
                                                const float* __restrict__ W2,
                                                u16* __restrict__ H) {
  __shared__ u16 wsb[16 * 144 * 8];       // B operand blocked [jb][n][r]
  __shared__ u16 uni[64 * 146];           // union: xs[64][136] then hs[64][146]
  u16* xs = uni;
  u16* hs = uni;
  const int tid = threadIdx.x;
  const int r0 = blockIdx.x * 64;         // global row in [0,32768)

  // stage B operand: [P1 | W2] -> blocked bf16
  for (int i = 0; i < 72; ++i) {
    int e = i * 256 + tid;                // (k, nn) row-major, 128x144
    int k = e / 144, nn = e % 144;
    float v = (nn < 128) ? P1f[k * 128 + nn] : W2[k * 16 + (nn - 128)];
    wsb[((k >> 3) * 144 + nn) * 8 + (k & 7)] = f2bf(v);
  }
  // stage x rows -> xs[64][136] bf16
  {
    const float* xp = x + ((size_t)(r0 + (tid >> 2))) * 128 + (tid & 3) * 32;
    u16* xd = xs + (tid >> 2) * 136 + (tid & 3) * 32;
#pragma unroll
    for (int i = 0; i < 4; ++i) {
      f32x4 a = ((const f32x4*)xp)[i * 2];
      f32x4 b = ((const f32x4*)xp)[i * 2 + 1];
      short8 pk;
      pk[0] = (short)f2bf(a[0]); pk[1] = (short)f2bf(a[1]);
      pk[2] = (short)f2bf(a[2]); pk[3] = (short)f2bf(a[3]);
      pk[4] = (short)f2bf(b[0]); pk[5] = (short)f2bf(b[1]);
      pk[6] = (short)f2bf(b[2]); pk[7] = (short)f2bf(b[3]);
      *(short8*)(xd + i * 8) = pk;
    }
  }
  __syncthreads();

  const int w = tid >> 6, l = tid & 63, lr = l & 15, lg = l >> 4;
  f32x4 acc[9];
  f32x4 zz = {0.f, 0.f, 0.f, 0.f};
#pragma unroll
  for (int fn = 0; fn < 9; ++fn) acc[fn] = zz;
#pragma unroll
  for (int kf = 0; kf < 4; ++kf) {
    short8 af = *(const short8*)(xs + (w * 16 + lr) * 136 + kf * 32 + lg * 8);
#pragma unroll
    for (int fn = 0; fn < 9; ++fn) {
      short8 bf = *(const short8*)(wsb + (((kf * 4 + lg) * 144) + fn * 16 + lr) * 8);
      acc[fn] = MFMA(af, bf, acc[fn], 0, 0, 0);
    }
  }
  __syncthreads();
  // write hs[64][146] bf16
#pragma unroll
  for (int fn = 0; fn < 9; ++fn)
#pragma unroll
    for (int g = 0; g < 4; ++g)
      hs[(w * 16 + lg * 4 + g) * 146 + fn * 16 + lr] = f2bf(acc[fn][g]);
  __syncthreads();
  // fragment-major coalesced write to H
  {
    const int b = r0 >> 12;
    const int kt = (r0 & 4095) >> 6;
    for (int i = 0; i < 5; ++i) {
      int e = i * 256 + tid;
      if (e < 1152) {
        int jbl = e / 144, n = e % 144;
        union { u16 s[8]; uint4 v; } pk;
#pragma unroll
        for (int r = 0; r < 8; ++r) pk.s[r] = hs[(jbl * 8 + r) * 146 + n];
        int kf = jbl >> 2, lgw = jbl & 3, fn = n >> 4, lrw = n & 15;
        size_t di = ((((size_t)kt * 2 + kf) * 8 + b) * 9 + fn) * 512 + (lgw * 16 + lrw) * 8;
        *(uint4*)(H + di) = pk.v;
      }
    }
  }
}

// expand 8 mask bits (byte lgsh/8 of a 32-bit half-word) -> 8 bf16 {0,1} packed as short8
__device__ __forceinline__ short8 expand_byte(uint32_t wd, int lgsh) {
  uint32_t b = (wd >> lgsh) & 0xFFu;     // v_bfe
  uint32_t t = b * 0x8001u;              // low half = b, bits16.. = b>>1
  union { uint32_t u[4]; short8 s; } r;
  r.u[0] = (t & 0x00010001u) * 0x3F80u;  // bits 0,1
  r.u[1] = (t & 0x00040004u) * 0x0FE0u;  // bits 2,3
  r.u[2] = (t & 0x00100010u) * 0x03F8u;  // bits 4,5
  r.u[3] = (t & 0x00400040u) * 0x00FEu;  // bits 6,7
  return r.s;
}

// ---------------- kernel B1: out = m1@u1 + (m2@h2)@Wb2 + rs1*q1 + rs2*q2 + bb ----------------
// grid 256 (b = bid&7 XCD-pinned -> 1 block/CU), 512 threads = 8 waves, NO main-loop barriers/LDS.
// wave w owns output col-tile fn=w (acc[fm=0..7]) + m2 fm=w (acc2, both kf in-register).
// Double-buffer is MANUAL with named A/B register sets (rule #20: no runtime-indexed arrays).
__global__ __launch_bounds__(512, 2) void kb1(const u16* __restrict__ H,
                                              const uint2* __restrict__ M1,
                                              const uint2* __restrict__ M2,
                                              const float* __restrict__ rs1, const float* __restrict__ rs2,
                                              const float* __restrict__ q1, const float* __restrict__ q2,
                                              const float* __restrict__ Wb, const float* __restrict__ bb,
                                              float* __restrict__ out) {
  __shared__ u16 f2s[128 * 40];            // f2 bf16, K padded to 32 (10 KB)
  __shared__ u16 wb2s[4096];               // Wb2 padded to K=32, fragment-blocked (8 KB)

  const int tid = threadIdx.x;
  const int bid = blockIdx.x;
  const int b = bid & 7;
  const int i0 = (bid >> 3) * 128;

  // stage Wb2 once (rows 128..143 of Wb, zero-padded to K=32)
#pragma unroll
  for (int i = 0; i < 8; ++i) {
    int e = i * 512 + tid;                // (jb*128+n)*8 + r
    int r_ = e & 7, nn = (e >> 3) & 127, jb = e >> 10;
    int k = jb * 8 + r_;
    wb2s[e] = f2bf((k < 16) ? Wb[(128 + k) * 128 + nn] : 0.f);
  }

  const int w = tid >> 6, l = tid & 63, lr = l & 15, lg = l >> 4;
  const int lgsh = lg * 8;

  // B-fragment pointers: frag(kt,kf,fn) base = (((kt*2+kf)*8 + b)*9 + fn)*512
  const u16* fb0 = H + (((size_t)0 * 8 + b) * 9 + w) * 512 + l * 8;   // m1, kf=0
  const u16* fb1 = fb0 + 36864;                                       // m1, kf=1
  const u16* fm0 = H + (((size_t)0 * 8 + b) * 9 + 8) * 512 + l * 8;   // m2, kf=0
  const u16* fm1 = fm0 + 36864;                                       // m2, kf=1
  // mask pointers (transposed layout M[kt*4096 + row])
  const uint2* mp1 = M1 + i0 + lr;
  const uint2* mp2 = M2 + i0 + w * 16 + lr;

  f32x4 zz = {0.f, 0.f, 0.f, 0.f};
  f32x4 acc[8];
  f32x4 acc2 = zz;
#pragma unroll
  for (int fm = 0; fm < 8; ++fm) acc[fm] = zz;

  // ---- manual double-buffer: named register sets A and B ----
  short8 bfA0, bfA1, bmA0, bmA1;
  short8 bfB0, bfB1, bmB0, bmB1;
  uint2 cm1A[8], cm1B[8];                 // indexed ONLY by unrolled constants
  uint2 cm2A, cm2B;

  bfA0 = *(const short8*)fb0; bfA1 = *(const short8*)fb1;
  bmA0 = *(const short8*)fm0; bmA1 = *(const short8*)fm1;
#pragma unroll
  for (int fm = 0; fm < 8; ++fm) cm1A[fm] = mp1[fm * 16];
  cm2A = mp2[0];

  for (int kt = 0; kt < 64; kt += 2) {
    // prefetch kt+1 into set B (kt+1 <= 63 always)
    {
      const size_t ho = (size_t)(kt + 1) * 73728;
      bfB0 = *(const short8*)(fb0 + ho);
      bfB1 = *(const short8*)(fb1 + ho);
      bmB0 = *(const short8*)(fm0 + ho);
      bmB1 = *(const short8*)(fm1 + ho);
      const size_t mo = (size_t)(kt + 1) * 4096;
#pragma unroll
      for (int fm = 0; fm < 8; ++fm) cm1B[fm] = mp1[mo + fm * 16];
      cm2B = mp2[mo];
    }
    // compute kt from set A
#pragma unroll
    for (int fm = 0; fm < 8; ++fm) {
      acc[fm] = MFMA(expand_byte(cm1A[fm].x, lgsh), bfA0, acc[fm], 0, 0, 0);
      acc[fm] = MFMA(expand_byte(cm1A[fm].y, lgsh), bfA1, acc[fm], 0, 0, 0);
    }
    acc2 = MFMA(expand_byte(cm2A.x, lgsh), bmA0, acc2, 0, 0, 0);
    acc2 = MFMA(expand_byte(cm2A.y, lgsh), bmA1, acc2, 0, 0, 0);

    // prefetch kt+2 into set A
    if (kt + 2 < 64) {
      const size_t ho = (size_t)(kt + 2) * 73728;
      bfA0 = *(const short8*)(fb0 + ho);
      bfA1 = *(const short8*)(fb1 + ho);
      bmA0 = *(const short8*)(fm0 + ho);
      bmA1 = *(const short8*)(fm1 + ho);
      const size_t mo = (size_t)(kt + 2) * 4096;
#pragma unroll
      for (int fm = 0; fm < 8; ++fm) cm1A[fm] = mp1[mo + fm * 16];
      cm2A = mp2[mo];
    }
    // compute kt+1 from set B
#pragma unroll
    for (int fm = 0; fm < 8; ++fm) {
      acc[fm] = MFMA(expand_byte(cm1B[fm].x, lgsh), bfB0, acc[fm], 0, 0, 0);
      acc[fm] = MFMA(expand_byte(cm1B[fm].y, lgsh), bfB1, acc[fm], 0, 0, 0);
    }
    acc2 = MFMA(expand_byte(cm2B.x, lgsh), bmB0, acc2, 0, 0, 0);
    acc2 = MFMA(expand_byte(cm2B.y, lgsh), bmB1, acc2, 0, 0, 0);
  }

  // epilogue: f2 (= m2@h2) -> LDS bf16 tile (K padded to 32, stride 40), one barrier
#pragma unroll
  for (int j = 0; j < 4; ++j) {           // zero-pad cols 16..31 (128 rows x 16)
    int e = tid * 4 + j;
    f2s[(e >> 4) * 40 + 16 + (e & 15)] = 0;
  }
#pragma unroll
  for (int g = 0; g < 4; ++g)
    f2s[(w * 16 + lg * 4 + g) * 40 + lr] = f2bf(acc2[g]);
  __syncthreads();

  // epilogue MFMA: acc[fm] += f2frag(fm) x Wb2frag(fn=w)
  short8 bwb = *(const short8*)(wb2s + ((lg * 128) + w * 16 + lr) * 8);
#pragma unroll
  for (int fm = 0; fm < 8; ++fm) {
    short8 af = *(const short8*)(f2s + (fm * 16 + lr) * 40 + lg * 8);
    acc[fm] = MFMA(af, bwb, acc[fm], 0, 0, 0);
  }

  // final: + rs1*q1 + rs2*q2 + bb, store f32
  const int col = w * 16 + lr;
  const float q1v = q1[col], q2v = q2[col], bbv = bb[col];
#pragma unroll
  for (int fm = 0; fm < 8; ++fm)
#pragma unroll
    for (int g = 0; g < 4; ++g) {
      int row = fm * 16 + lg * 4 + g;
      float r1 = rs1[i0 + row], r2 = rs2[i0 + row];
      out[((size_t)b * 4096 + i0 + row) * 128 + col] = acc[fm][g] + r1 * q1v + r2 * q2v + bbv;
    }
}

extern "C" void kernel_launch(void* const* d_in, const int* in_sizes, int n_in,
                              void* d_out, int out_size, void* d_ws, size_t ws_size,
                              hipStream_t stream) {
  const float* x  = (const float*)d_in[0];
  const int*   sp = (const int*)d_in[1];
  const float* W1 = (const float*)d_in[2];
  const float* b1 = (const float*)d_in[3];
  const float* W2 = (const float*)d_in[4];
  const float* b2 = (const float*)d_in[5];
  const float* Wb = (const float*)d_in[6];
  const float* bb = (const float*)d_in[7];
  float* out = (float*)d_out;
  char* ws = (char*)d_ws;

  u16* H = (u16*)(ws + WS_H);
  float* P1 = (float*)(ws + WS_P1);
  float* q1 = (float*)(ws + WS_Q1);
  float* q2 = (float*)(ws + WS_Q2);
  unsigned long long* m1p = (unsigned long long*)(ws + WS_M1P);
  unsigned long long* m2p = (unsigned long long*)(ws + WS_M2P);
  float* rs1 = (float*)(ws + WS_RS1);
  float* rs2 = (float*)(ws + WS_RS2);

  kmask<<<1024, 256, 0, stream>>>(sp, m1p, m2p, rs1, rs2);
  kprep<<<64, 256, 0, stream>>>(W1, Wb, b1, b2, P1, q1, q2);
  kproj<<<512, 256, 0, stream>>>(x, P1, W2, H);
  kb1<<<256, 512, 0, stream>>>(H, (const uint2*)m1p, (const uint2*)m2p,
                               rs1, rs2, q1, q2, Wb, bb, out);
}

// Round 7
// 121.581 us; speedup vs baseline: 39.7750x; 1.0289x over previous
//
#include <hip/hip_runtime.h>
#include <stdint.h>

typedef unsigned short u16;
typedef __attribute__((ext_vector_type(8))) short short8;
typedef __attribute__((ext_vector_type(4))) float f32x4;

#define MFMA __builtin_amdgcn_mfma_f32_16x16x32_bf16

__device__ __forceinline__ u16 f2bf(float f) {
  union { float f; uint32_t u; } v; v.f = f;
  return (u16)((v.u + 0x7FFFu + ((v.u >> 16) & 1u)) >> 16);
}

// ws layout (bytes)
#define WS_H    0          // u16 H[64][2][8][9][64][8]  fragment-major (9,437,184 B)
#define WS_P1   9437184    // f32 P1[128][128]
#define WS_Q1   9502720    // f32 q1[128]
#define WS_Q2   9503232    // f32 q2[128]
#define WS_M1P  9503744    // u64 m1p[64][4096]   (TRANSPOSED: [kt][row])
#define WS_M2P  11600896   // u64 m2p[64][4096]
#define WS_RS1  13698048   // f32 rs1[4096]
#define WS_RS2  13714432   // f32 rs2[4096]

// ---------------- kernel M: pack masks into bits (transposed) + row sums ----------------
__global__ __launch_bounds__(256) void kmask(const int* __restrict__ sp,
                                             unsigned long long* __restrict__ m1p,
                                             unsigned long long* __restrict__ m2p,
                                             float* __restrict__ rs1, float* __restrict__ rs2) {
  int wave = threadIdx.x >> 6, lane = threadIdx.x & 63;
  int i = blockIdx.x * 4 + wave;
  const int* rowp = sp + (size_t)i * 4096;
  int c1 = 0, c2 = 0;
  for (int w = 0; w < 64; ++w) {
    int v = rowp[w * 64 + lane];
    unsigned long long b1 = __ballot(v <= 1);
    unsigned long long b2 = __ballot(v == 2);
    if (lane == 0) {
      m1p[(size_t)w * 4096 + i] = b1;   // [kt][row]
      m2p[(size_t)w * 4096 + i] = b2;
      c1 += __popcll(b1);
      c2 += __popcll(b2);
    }
  }
  if (lane == 0) { rs1[i] = (float)c1; rs2[i] = (float)c2; }
}

// ---------------- kernel P: P1 = W1 @ Wb1, q1 = b1@Wb1, q2 = b2@Wb2 ----------------
__global__ __launch_bounds__(256) void kprep(const float* __restrict__ W1, const float* __restrict__ Wb,
                                             const float* __restrict__ b1, const float* __restrict__ b2,
                                             float* __restrict__ P1, float* __restrict__ q1,
                                             float* __restrict__ q2) {
  int idx = blockIdx.x * 256 + threadIdx.x;   // 0..16383
  int a = idx >> 7, c = idx & 127;
  float acc = 0.f;
  for (int k = 0; k < 128; ++k) acc += W1[a * 128 + k] * Wb[k * 128 + c];
  P1[idx] = acc;
  if (idx < 128) {
    float s1 = 0.f, s2 = 0.f;
    for (int k = 0; k < 128; ++k) s1 += b1[k] * Wb[k * 128 + idx];
    for (int k = 0; k < 16; ++k)  s2 += b2[k] * Wb[(128 + k) * 128 + idx];
    q1[idx] = s1; q2[idx] = s2;
  }
}

// ---------------- kernel A': u1 = x@P1, h2 = x@W2 -> fragment-major H ----------------
// H element (kt,kf,b,fn,lane=lg*16+lr,r) = u1h2[b][kt*64+kf*32+lg*8+r][fn*16+lr]
__global__ __launch_bounds__(256, 2) void kproj(const float* __restrict__ x,
                                                const float* __restrict__ P1f,
                                                const float* __restrict__ W2,
                                                u16* __restrict__ H) {
  __shared__ u16 wsb[16 * 144 * 8];       // B operand blocked [jb][n][r]
  __shared__ u16 uni[64 * 146];           // union: xs[64][136] then hs[64][146]
  u16* xs = uni;
  u16* hs = uni;
  const int tid = threadIdx.x;
  const int r0 = blockIdx.x * 64;         // global row in [0,32768)

  // stage B operand: [P1 | W2] -> blocked bf16
  for (int i = 0; i < 72; ++i) {
    int e = i * 256 + tid;                // (k, nn) row-major, 128x144
    int k = e / 144, nn = e % 144;
    float v = (nn < 128) ? P1f[k * 128 + nn] : W2[k * 16 + (nn - 128)];
    wsb[((k >> 3) * 144 + nn) * 8 + (k & 7)] = f2bf(v);
  }
  // stage x rows -> xs[64][136] bf16
  {
    const float* xp = x + ((size_t)(r0 + (tid >> 2))) * 128 + (tid & 3) * 32;
    u16* xd = xs + (tid >> 2) * 136 + (tid & 3) * 32;
#pragma unroll
    for (int i = 0; i < 4; ++i) {
      f32x4 a = ((const f32x4*)xp)[i * 2];
      f32x4 b = ((const f32x4*)xp)[i * 2 + 1];
      short8 pk;
      pk[0] = (short)f2bf(a[0]); pk[1] = (short)f2bf(a[1]);
      pk[2] = (short)f2bf(a[2]); pk[3] = (short)f2bf(a[3]);
      pk[4] = (short)f2bf(b[0]); pk[5] = (short)f2bf(b[1]);
      pk[6] = (short)f2bf(b[2]); pk[7] = (short)f2bf(b[3]);
      *(short8*)(xd + i * 8) = pk;
    }
  }
  __syncthreads();

  const int w = tid >> 6, l = tid & 63, lr = l & 15, lg = l >> 4;
  f32x4 acc[9];
  f32x4 zz = {0.f, 0.f, 0.f, 0.f};
#pragma unroll
  for (int fn = 0; fn < 9; ++fn) acc[fn] = zz;
#pragma unroll
  for (int kf = 0; kf < 4; ++kf) {
    short8 af = *(const short8*)(xs + (w * 16 + lr) * 136 + kf * 32 + lg * 8);
#pragma unroll
    for (int fn = 0; fn < 9; ++fn) {
      short8 bf = *(const short8*)(wsb + (((kf * 4 + lg) * 144) + fn * 16 + lr) * 8);
      acc[fn] = MFMA(af, bf, acc[fn], 0, 0, 0);
    }
  }
  __syncthreads();
  // write hs[64][146] bf16
#pragma unroll
  for (int fn = 0; fn < 9; ++fn)
#pragma unroll
    for (int g = 0; g < 4; ++g)
      hs[(w * 16 + lg * 4 + g) * 146 + fn * 16 + lr] = f2bf(acc[fn][g]);
  __syncthreads();
  // fragment-major coalesced write to H
  {
    const int b = r0 >> 12;
    const int kt = (r0 & 4095) >> 6;
    for (int i = 0; i < 5; ++i) {
      int e = i * 256 + tid;
      if (e < 1152) {
        int jbl = e / 144, n = e % 144;
        union { u16 s[8]; uint4 v; } pk;
#pragma unroll
        for (int r = 0; r < 8; ++r) pk.s[r] = hs[(jbl * 8 + r) * 146 + n];
        int kf = jbl >> 2, lgw = jbl & 3, fn = n >> 4, lrw = n & 15;
        size_t di = ((((size_t)kt * 2 + kf) * 8 + b) * 9 + fn) * 512 + (lgw * 16 + lrw) * 8;
        *(uint4*)(H + di) = pk.v;
      }
    }
  }
}

// expand 8 mask bits (byte lgsh/8 of a 32-bit half-word) -> 8 bf16 {0,1} packed as short8
__device__ __forceinline__ short8 expand_byte(uint32_t wd, int lgsh) {
  uint32_t b = (wd >> lgsh) & 0xFFu;     // v_bfe
  uint32_t t = b * 0x8001u;              // low half = b, bits16.. = b>>1
  union { uint32_t u[4]; short8 s; } r;
  r.u[0] = (t & 0x00010001u) * 0x3F80u;  // bits 0,1
  r.u[1] = (t & 0x00040004u) * 0x0FE0u;  // bits 2,3
  r.u[2] = (t & 0x00100010u) * 0x03F8u;  // bits 4,5
  r.u[3] = (t & 0x00400040u) * 0x00FEu;  // bits 6,7
  return r.s;
}

// ---------------- kernel B1: out = m1@u1 + (m2@h2)@Wb2 + rs1*q1 + rs2*q2 + bb ----------------
// grid 512 (b = bid&7 XCD-pinned, panel = bid>>3 = 64 rows) -> 2 blocks/CU, 4 waves/SIMD.
// 8 waves; wave (g=w>>2, c=w&3): m1 fm {2g,2g+1} x fn {2c,2c+1}; m2 (fm2=w&3, kf2=w>>2).
// One expand feeds 2 MFMAs. Manual named A/B double-buffer (no runtime-indexed arrays).
__global__ __launch_bounds__(512, 4) void kb1(const u16* __restrict__ H,
                                              const uint2* __restrict__ M1,
                                              const uint32_t* __restrict__ M2w,
                                              const float* __restrict__ rs1, const float* __restrict__ rs2,
                                              const float* __restrict__ q1, const float* __restrict__ q2,
                                              const float* __restrict__ Wb, const float* __restrict__ bb,
                                              float* __restrict__ out) {
  __shared__ float f2pf[2][64][16];        // m2@h2 kf-partials (8 KB)
  __shared__ u16 f2s[64 * 40];             // f2 bf16, K padded to 32 (5 KB)
  __shared__ u16 wb2s[4096];               // Wb2 padded to K=32, fragment-blocked (8 KB)

  const int tid = threadIdx.x;
  const int bid = blockIdx.x;
  const int b = bid & 7;
  const int i0 = (bid >> 3) * 64;

  // stage Wb2 once (rows 128..143 of Wb, zero-padded to K=32)
#pragma unroll
  for (int i = 0; i < 8; ++i) {
    int e = i * 512 + tid;                // (jb*128+n)*8 + r
    int r_ = e & 7, nn = (e >> 3) & 127, jb = e >> 10;
    int k = jb * 8 + r_;
    wb2s[e] = f2bf((k < 16) ? Wb[(128 + k) * 128 + nn] : 0.f);
  }

  const int w = tid >> 6, l = tid & 63, lr = l & 15, lg = l >> 4;
  const int g = w >> 2, c = w & 3;
  const int fm2 = w & 3, kf2 = w >> 2;
  const int lgsh = lg * 8;

  // B-fragment pointers: frag(kt,kf,fn) base = (((kt*2+kf)*8 + b)*9 + fn)*512
  const u16* f00 = H + (((size_t)0 * 8 + b) * 9 + (c * 2 + 0)) * 512 + l * 8;  // kf0,fn even
  const u16* f01 = H + (((size_t)0 * 8 + b) * 9 + (c * 2 + 1)) * 512 + l * 8;  // kf0,fn odd
  const u16* f10 = f00 + 36864;                                                // kf1,fn even
  const u16* f11 = f01 + 36864;                                                // kf1,fn odd
  const u16* fmm = H + (((size_t)kf2 * 8 + b) * 9 + 8) * 512 + l * 8;          // m2, kf=kf2
  // mask pointers (transposed layout M[kt*4096 + row])
  const uint2* mp1a = M1 + i0 + (g * 2 + 0) * 16 + lr;
  const uint2* mp1b = M1 + i0 + (g * 2 + 1) * 16 + lr;
  const uint32_t* mp2 = M2w + (size_t)(i0 + fm2 * 16 + lr) * 2 + kf2;

  f32x4 zz = {0.f, 0.f, 0.f, 0.f};
  f32x4 acc00 = zz, acc01 = zz, acc10 = zz, acc11 = zz;  // [i][fj]
  f32x4 acc2 = zz;

  // ---- manual double-buffer: named register sets A and B ----
  short8 bA00, bA01, bA10, bA11, bAm;
  short8 bB00, bB01, bB10, bB11, bBm;
  uint2 cA0, cA1, cB0, cB1;
  uint32_t cA2, cB2;

  bA00 = *(const short8*)f00; bA01 = *(const short8*)f01;
  bA10 = *(const short8*)f10; bA11 = *(const short8*)f11;
  bAm  = *(const short8*)fmm;
  cA0 = mp1a[0]; cA1 = mp1b[0]; cA2 = mp2[0];

  for (int kt = 0; kt < 64; kt += 2) {
    // prefetch kt+1 into set B
    {
      const size_t ho = (size_t)(kt + 1) * 73728;
      bB00 = *(const short8*)(f00 + ho); bB01 = *(const short8*)(f01 + ho);
      bB10 = *(const short8*)(f10 + ho); bB11 = *(const short8*)(f11 + ho);
      bBm  = *(const short8*)(fmm + ho);
      const size_t mo = (size_t)(kt + 1) * 4096;
      cB0 = mp1a[mo]; cB1 = mp1b[mo]; cB2 = mp2[(size_t)(kt + 1) * 8192];
    }
    // compute kt from set A
    {
      short8 e0x = expand_byte(cA0.x, lgsh), e0y = expand_byte(cA0.y, lgsh);
      short8 e1x = expand_byte(cA1.x, lgsh), e1y = expand_byte(cA1.y, lgsh);
      acc00 = MFMA(e0x, bA00, acc00, 0, 0, 0);
      acc01 = MFMA(e0x, bA01, acc01, 0, 0, 0);
      acc00 = MFMA(e0y, bA10, acc00, 0, 0, 0);
      acc01 = MFMA(e0y, bA11, acc01, 0, 0, 0);
      acc10 = MFMA(e1x, bA00, acc10, 0, 0, 0);
      acc11 = MFMA(e1x, bA01, acc11, 0, 0, 0);
      acc10 = MFMA(e1y, bA10, acc10, 0, 0, 0);
      acc11 = MFMA(e1y, bA11, acc11, 0, 0, 0);
      acc2  = MFMA(expand_byte(cA2, lgsh), bAm, acc2, 0, 0, 0);
    }
    // prefetch kt+2 into set A
    if (kt + 2 < 64) {
      const size_t ho = (size_t)(kt + 2) * 73728;
      bA00 = *(const short8*)(f00 + ho); bA01 = *(const short8*)(f01 + ho);
      bA10 = *(const short8*)(f10 + ho); bA11 = *(const short8*)(f11 + ho);
      bAm  = *(const short8*)(fmm + ho);
      const size_t mo = (size_t)(kt + 2) * 4096;
      cA0 = mp1a[mo]; cA1 = mp1b[mo]; cA2 = mp2[(size_t)(kt + 2) * 8192];
    }
    // compute kt+1 from set B
    {
      short8 e0x = expand_byte(cB0.x, lgsh), e0y = expand_byte(cB0.y, lgsh);
      short8 e1x = expand_byte(cB1.x, lgsh), e1y = expand_byte(cB1.y, lgsh);
      acc00 = MFMA(e0x, bB00, acc00, 0, 0, 0);
      acc01 = MFMA(e0x, bB01, acc01, 0, 0, 0);
      acc00 = MFMA(e0y, bB10, acc00, 0, 0, 0);
      acc01 = MFMA(e0y, bB11, acc01, 0, 0, 0);
      acc10 = MFMA(e1x, bB00, acc10, 0, 0, 0);
      acc11 = MFMA(e1x, bB01, acc11, 0, 0, 0);
      acc10 = MFMA(e1y, bB10, acc10, 0, 0, 0);
      acc11 = MFMA(e1y, bB11, acc11, 0, 0, 0);
      acc2  = MFMA(expand_byte(cB2, lgsh), bBm, acc2, 0, 0, 0);
    }
  }

  // epilogue: combine m2 kf-partials -> f2 bf16 tile
#pragma unroll
  for (int gg = 0; gg < 4; ++gg)
    f2pf[kf2][fm2 * 16 + lg * 4 + gg][lr] = acc2[gg];
  __syncthreads();
#pragma unroll
  for (int j = 0; j < 2; ++j) {
    int e = j * 512 + tid;                 // 64x16 = 1024 elems
    int row = e >> 4, col = e & 15;
    f2s[row * 40 + col] = f2bf(f2pf[0][row][col] + f2pf[1][row][col]);
    f2s[row * 40 + 16 + col] = 0;          // zero-pad cols 16..31
  }
  __syncthreads();

  // epilogue MFMA: acc[i][fj] += f2frag(fm=2g+i) x Wb2frag(fn=2c+fj)
  short8 bw0 = *(const short8*)(wb2s + ((lg * 128) + (c * 2 + 0) * 16 + lr) * 8);
  short8 bw1 = *(const short8*)(wb2s + ((lg * 128) + (c * 2 + 1) * 16 + lr) * 8);
  {
    short8 af0 = *(const short8*)(f2s + ((g * 2 + 0) * 16 + lr) * 40 + lg * 8);
    short8 af1 = *(const short8*)(f2s + ((g * 2 + 1) * 16 + lr) * 40 + lg * 8);
    acc00 = MFMA(af0, bw0, acc00, 0, 0, 0);
    acc01 = MFMA(af0, bw1, acc01, 0, 0, 0);
    acc10 = MFMA(af1, bw0, acc10, 0, 0, 0);
    acc11 = MFMA(af1, bw1, acc11, 0, 0, 0);
  }

  // final: + rs1*q1 + rs2*q2 + bb, store f32
  const int col0 = (c * 2 + 0) * 16 + lr, col1 = (c * 2 + 1) * 16 + lr;
  const float q10 = q1[col0], q20 = q2[col0], bb0 = bb[col0];
  const float q11 = q1[col1], q21 = q2[col1], bb1 = bb[col1];
#pragma unroll
  for (int i = 0; i < 2; ++i) {
    f32x4 a0 = i ? acc10 : acc00;
    f32x4 a1 = i ? acc11 : acc01;
#pragma unroll
    for (int gg = 0; gg < 4; ++gg) {
      int row = (g * 2 + i) * 16 + lg * 4 + gg;
      float r1 = rs1[i0 + row], r2 = rs2[i0 + row];
      size_t obase = ((size_t)b * 4096 + i0 + row) * 128;
      out[obase + col0] = a0[gg] + r1 * q10 + r2 * q20 + bb0;
      out[obase + col1] = a1[gg] + r1 * q11 + r2 * q21 + bb1;
    }
  }
}

extern "C" void kernel_launch(void* const* d_in, const int* in_sizes, int n_in,
                              void* d_out, int out_size, void* d_ws, size_t ws_size,
                              hipStream_t stream) {
  const float* x  = (const float*)d_in[0];
  const int*   sp = (const int*)d_in[1];
  const float* W1 = (const float*)d_in[2];
  const float* b1 = (const float*)d_in[3];
  const float* W2 = (const float*)d_in[4];
  const float* b2 = (const float*)d_in[5];
  const float* Wb = (const float*)d_in[6];
  const float* bb = (const float*)d_in[7];
  float* out = (float*)d_out;
  char* ws = (char*)d_ws;

  u16* H = (u16*)(ws + WS_H);
  float* P1 = (float*)(ws + WS_P1);
  float* q1 = (float*)(ws + WS_Q1);
  float* q2 = (float*)(ws + WS_Q2);
  unsigned long long* m1p = (unsigned long long*)(ws + WS_M1P);
  unsigned long long* m2p = (unsigned long long*)(ws + WS_M2P);
  float* rs1 = (float*)(ws + WS_RS1);
  float* rs2 = (float*)(ws + WS_RS2);

  kmask<<<1024, 256, 0, stream>>>(sp, m1p, m2p, rs1, rs2);
  kprep<<<64, 256, 0, stream>>>(W1, Wb, b1, b2, P1, q1, q2);
  kproj<<<512, 256, 0, stream>>>(x, P1, W2, H);
  kb1<<<512, 512, 0, stream>>>(H, (const uint2*)m1p, (const uint32_t*)m2p,
                               rs1, rs2, q1, q2, Wb, bb, out);
}

// Round 8
// 113.116 us; speedup vs baseline: 42.7517x; 1.0748x over previous
//
#include <hip/hip_runtime.h>
#include <stdint.h>

typedef unsigned short u16;
typedef __attribute__((ext_vector_type(8))) short short8;
typedef __attribute__((ext_vector_type(4))) float f32x4;

#define MFMA __builtin_amdgcn_mfma_f32_16x16x32_bf16

__device__ __forceinline__ u16 f2bf(float f) {
  union { float f; uint32_t u; } v; v.f = f;
  return (u16)((v.u + 0x7FFFu + ((v.u >> 16) & 1u)) >> 16);
}

#define GLOAD16(gp, lp) \
  __builtin_amdgcn_global_load_lds((const __attribute__((address_space(1))) uint32_t*)(gp), \
                                   (__attribute__((address_space(3))) uint32_t*)(lp), 16, 0, 0)

// ws layout (bytes)
#define WS_H    0          // u16 H[64][2][8][9][64][8]  fragment-major (9,437,184 B)
#define WS_P1   9437184    // f32 P1[128][128]
#define WS_Q1   9502720    // f32 q1[128]
#define WS_Q2   9503232    // f32 q2[128]
#define WS_M1P  9503744    // u64 m1p[64][4096]   (TRANSPOSED: [kt][row])
#define WS_M2P  11600896   // u64 m2p[64][4096]
#define WS_RS1  13698048   // f32 rs1[4096]
#define WS_RS2  13714432   // f32 rs2[4096]

// ---------------- kernel M: pack masks into bits (transposed) + row sums ----------------
__global__ __launch_bounds__(256) void kmask(const int* __restrict__ sp,
                                             unsigned long long* __restrict__ m1p,
                                             unsigned long long* __restrict__ m2p,
                                             float* __restrict__ rs1, float* __restrict__ rs2) {
  int wave = threadIdx.x >> 6, lane = threadIdx.x & 63;
  int i = blockIdx.x * 4 + wave;
  const int* rowp = sp + (size_t)i * 4096;
  int c1 = 0, c2 = 0;
  for (int w = 0; w < 64; ++w) {
    int v = rowp[w * 64 + lane];
    unsigned long long b1 = __ballot(v <= 1);
    unsigned long long b2 = __ballot(v == 2);
    if (lane == 0) {
      m1p[(size_t)w * 4096 + i] = b1;   // [kt][row]
      m2p[(size_t)w * 4096 + i] = b2;
      c1 += __popcll(b1);
      c2 += __popcll(b2);
    }
  }
  if (lane == 0) { rs1[i] = (float)c1; rs2[i] = (float)c2; }
}

// ---------------- kernel P: P1 = W1 @ Wb1, q1 = b1@Wb1, q2 = b2@Wb2 ----------------
__global__ __launch_bounds__(256) void kprep(const float* __restrict__ W1, const float* __restrict__ Wb,
                                             const float* __restrict__ b1, const float* __restrict__ b2,
                                             float* __restrict__ P1, float* __restrict__ q1,
                                             float* __restrict__ q2) {
  int idx = blockIdx.x * 256 + threadIdx.x;   // 0..16383
  int a = idx >> 7, c = idx & 127;
  float acc = 0.f;
  for (int k = 0; k < 128; ++k) acc += W1[a * 128 + k] * Wb[k * 128 + c];
  P1[idx] = acc;
  if (idx < 128) {
    float s1 = 0.f, s2 = 0.f;
    for (int k = 0; k < 128; ++k) s1 += b1[k] * Wb[k * 128 + idx];
    for (int k = 0; k < 16; ++k)  s2 += b2[k] * Wb[(128 + k) * 128 + idx];
    q1[idx] = s1; q2[idx] = s2;
  }
}

// ---------------- kernel A': u1 = x@P1, h2 = x@W2 -> fragment-major H ----------------
// H element (kt,kf,b,fn,lane=lg*16+lr,r) = u1h2[b][kt*64+kf*32+lg*8+r][fn*16+lr]
__global__ __launch_bounds__(256, 2) void kproj(const float* __restrict__ x,
                                                const float* __restrict__ P1f,
                                                const float* __restrict__ W2,
                                                u16* __restrict__ H) {
  __shared__ u16 wsb[16 * 144 * 8];       // B operand blocked [jb][n][r]
  __shared__ u16 uni[64 * 146];           // union: xs[64][136] then hs[64][146]
  u16* xs = uni;
  u16* hs = uni;
  const int tid = threadIdx.x;
  const int r0 = blockIdx.x * 64;         // global row in [0,32768)

  // stage B operand: [P1 | W2] -> blocked bf16
  for (int i = 0; i < 72; ++i) {
    int e = i * 256 + tid;                // (k, nn) row-major, 128x144
    int k = e / 144, nn = e % 144;
    float v = (nn < 128) ? P1f[k * 128 + nn] : W2[k * 16 + (nn - 128)];
    wsb[((k >> 3) * 144 + nn) * 8 + (k & 7)] = f2bf(v);
  }
  // stage x rows -> xs[64][136] bf16
  {
    const float* xp = x + ((size_t)(r0 + (tid >> 2))) * 128 + (tid & 3) * 32;
    u16* xd = xs + (tid >> 2) * 136 + (tid & 3) * 32;
#pragma unroll
    for (int i = 0; i < 4; ++i) {
      f32x4 a = ((const f32x4*)xp)[i * 2];
      f32x4 b = ((const f32x4*)xp)[i * 2 + 1];
      short8 pk;
      pk[0] = (short)f2bf(a[0]); pk[1] = (short)f2bf(a[1]);
      pk[2] = (short)f2bf(a[2]); pk[3] = (short)f2bf(a[3]);
      pk[4] = (short)f2bf(b[0]); pk[5] = (short)f2bf(b[1]);
      pk[6] = (short)f2bf(b[2]); pk[7] = (short)f2bf(b[3]);
      *(short8*)(xd + i * 8) = pk;
    }
  }
  __syncthreads();

  const int w = tid >> 6, l = tid & 63, lr = l & 15, lg = l >> 4;
  f32x4 acc[9];
  f32x4 zz = {0.f, 0.f, 0.f, 0.f};
#pragma unroll
  for (int fn = 0; fn < 9; ++fn) acc[fn] = zz;
#pragma unroll
  for (int kf = 0; kf < 4; ++kf) {
    short8 af = *(const short8*)(xs + (w * 16 + lr) * 136 + kf * 32 + lg * 8);
#pragma unroll
    for (int fn = 0; fn < 9; ++fn) {
      short8 bf = *(const short8*)(wsb + (((kf * 4 + lg) * 144) + fn * 16 + lr) * 8);
      acc[fn] = MFMA(af, bf, acc[fn], 0, 0, 0);
    }
  }
  __syncthreads();
  // write hs[64][146] bf16
#pragma unroll
  for (int fn = 0; fn < 9; ++fn)
#pragma unroll
    for (int g = 0; g < 4; ++g)
      hs[(w * 16 + lg * 4 + g) * 146 + fn * 16 + lr] = f2bf(acc[fn][g]);
  __syncthreads();
  // fragment-major coalesced write to H
  {
    const int b = r0 >> 12;
    const int kt = (r0 & 4095) >> 6;
    for (int i = 0; i < 5; ++i) {
      int e = i * 256 + tid;
      if (e < 1152) {
        int jbl = e / 144, n = e % 144;
        union { u16 s[8]; uint4 v; } pk;
#pragma unroll
        for (int r = 0; r < 8; ++r) pk.s[r] = hs[(jbl * 8 + r) * 146 + n];
        int kf = jbl >> 2, lgw = jbl & 3, fn = n >> 4, lrw = n & 15;
        size_t di = ((((size_t)kt * 2 + kf) * 8 + b) * 9 + fn) * 512 + (lgw * 16 + lrw) * 8;
        *(uint4*)(H + di) = pk.v;
      }
    }
  }
}

// expand 8 mask bits (byte lgsh/8 of a 32-bit half-word) -> 8 bf16 {0,1} packed as short8
__device__ __forceinline__ short8 expand_byte(uint32_t wd, int lgsh) {
  uint32_t b = (wd >> lgsh) & 0xFFu;     // v_bfe
  uint32_t t = b * 0x8001u;              // low half = b, bits16.. = b>>1
  union { uint32_t u[4]; short8 s; } r;
  r.u[0] = (t & 0x00010001u) * 0x3F80u;  // bits 0,1
  r.u[1] = (t & 0x00040004u) * 0x0FE0u;  // bits 2,3
  r.u[2] = (t & 0x00100010u) * 0x03F8u;  // bits 4,5
  r.u[3] = (t & 0x00400040u) * 0x00FEu;  // bits 6,7
  return r.s;
}

// ---------------- kernel B1: out = m1@u1 + (m2@h2)@Wb2 + rs1*q1 + rs2*q2 + bb ----------------
// grid 512 (b = bid&7 XCD-pinned, panel = bid>>3 = 64 rows) -> 2 blocks/CU.
// B-fragments staged to LDS via global_load_lds (double buffer, 1 barrier/kt; no register residency).
// 8 waves; wave (g=w>>2, c=w&3): m1 fm {2g,2g+1} x fn {2c,2c+1}; m2 (fm2=w&3, kf2=w>>2).
__global__ __launch_bounds__(512, 4) void kb1(const u16* __restrict__ H,
                                              const uint2* __restrict__ M1,
                                              const uint32_t* __restrict__ M2w,
                                              const float* __restrict__ rs1, const float* __restrict__ rs2,
                                              const float* __restrict__ q1, const float* __restrict__ q2,
                                              const float* __restrict__ Wb, const float* __restrict__ bb,
                                              float* __restrict__ out) {
  __shared__ u16 bt[2][9216];              // double-buffered B tile (36 KB)
  __shared__ float f2pf[2][64][16];        // m2@h2 kf-partials (8 KB)
  __shared__ u16 f2s[64 * 40];             // f2 bf16, K padded to 32 (5 KB)
  __shared__ u16 wb2s[4096];               // Wb2 padded to K=32, fragment-blocked (8 KB)

  const int tid = threadIdx.x;
  const int bid = blockIdx.x;
  const int b = bid & 7;
  const int i0 = (bid >> 3) * 64;

  // stage Wb2 once (rows 128..143 of Wb, zero-padded to K=32)
#pragma unroll
  for (int i = 0; i < 8; ++i) {
    int e = i * 512 + tid;                // (jb*128+n)*8 + r
    int r_ = e & 7, nn = (e >> 3) & 127, jb = e >> 10;
    int k = jb * 8 + r_;
    wb2s[e] = f2bf((k < 16) ? Wb[(128 + k) * 128 + nn] : 0.f);
  }

  const int w = tid >> 6, l = tid & 63, lr = l & 15, lg = l >> 4;
  const int g = w >> 2, c = w & 3;
  const int fm2 = w & 3, kf2 = w >> 2;
  const int lgsh = lg * 8;

  // stage source offsets (u16 units within a kt-slab, b folded in).
  // kt-slab: kf0 4608 u16 at +b*4608; kf1 4608 u16 at +36864+b*4608.
  const int e0 = tid * 8;
  const int e1 = 4096 + tid * 8;
  const int e2 = 8192 + tid * 8;
  const uint32_t soff0 = b * 4608 + e0;                              // always kf0
  const uint32_t soff1 = b * 4608 + (uint32_t)(e1 < 4608 ? e1 : 32256 + e1);
  const uint32_t soff2 = b * 4608 + 32256 + e2;                      // always kf1 (tid<128)

  // mask pointers (transposed layout M[kt*4096 + row])
  const uint2* mp1a = M1 + i0 + (g * 2 + 0) * 16 + lr;
  const uint2* mp1b = M1 + i0 + (g * 2 + 1) * 16 + lr;
  const uint32_t* mp2 = M2w + (size_t)(i0 + fm2 * 16 + lr) * 2 + kf2;

  // compute-phase LDS offsets (u16)
  const int fA0 = (c * 2 + 0) * 512 + l * 8;            // kf0, fn even
  const int fA1 = (c * 2 + 1) * 512 + l * 8;            // kf0, fn odd
  const int fB0 = 4608 + fA0;                           // kf1, fn even
  const int fB1 = 4608 + fA1;                           // kf1, fn odd
  const int fM  = kf2 * 4608 + 8 * 512 + l * 8;         // m2 frag

  f32x4 zz = {0.f, 0.f, 0.f, 0.f};
  f32x4 acc00 = zz, acc01 = zz, acc10 = zz, acc11 = zz;
  f32x4 acc2 = zz;

  // named mask sets (A = even kt, B = odd kt)
  uint2 cA0, cA1, cB0, cB1;
  uint32_t cA2, cB2;

  // prologue: stage kt=0 -> bt[0]; load kt=0 masks -> A
  {
    const u16* hp = H;                     // kt=0 slab base
    GLOAD16(hp + soff0, (char*)&bt[0][0] + (size_t)e0 * 2);
    GLOAD16(hp + soff1, (char*)&bt[0][0] + (size_t)e1 * 2);
    if (tid < 128)
      GLOAD16(hp + soff2, (char*)&bt[0][0] + (size_t)e2 * 2);
  }
  cA0 = mp1a[0]; cA1 = mp1b[0]; cA2 = mp2[0];

  for (int kt = 0; kt < 64; kt += 2) {
    // ---- even phase: compute kt from bt[0], masks A ----
    __syncthreads();                       // drains stage(kt -> bt[0])
    {                                      // stage kt+1 -> bt[1]  (kt+1 <= 63 always)
      const u16* hp = H + (size_t)(kt + 1) * 73728;
      GLOAD16(hp + soff0, (char*)&bt[1][0] + (size_t)e0 * 2);
      GLOAD16(hp + soff1, (char*)&bt[1][0] + (size_t)e1 * 2);
      if (tid < 128)
        GLOAD16(hp + soff2, (char*)&bt[1][0] + (size_t)e2 * 2);
      const size_t mo = (size_t)(kt + 1) * 4096;
      cB0 = mp1a[mo]; cB1 = mp1b[mo]; cB2 = mp2[(size_t)(kt + 1) * 8192];
    }
    {
      const u16* src = &bt[0][0];
      short8 e0x = expand_byte(cA0.x, lgsh), e0y = expand_byte(cA0.y, lgsh);
      short8 e1x = expand_byte(cA1.x, lgsh), e1y = expand_byte(cA1.y, lgsh);
      short8 bA0 = *(const short8*)(src + fA0);
      short8 bA1 = *(const short8*)(src + fA1);
      short8 bB0 = *(const short8*)(src + fB0);
      short8 bB1 = *(const short8*)(src + fB1);
      short8 bM  = *(const short8*)(src + fM);
      acc00 = MFMA(e0x, bA0, acc00, 0, 0, 0);
      acc01 = MFMA(e0x, bA1, acc01, 0, 0, 0);
      acc00 = MFMA(e0y, bB0, acc00, 0, 0, 0);
      acc01 = MFMA(e0y, bB1, acc01, 0, 0, 0);
      acc10 = MFMA(e1x, bA0, acc10, 0, 0, 0);
      acc11 = MFMA(e1x, bA1, acc11, 0, 0, 0);
      acc10 = MFMA(e1y, bB0, acc10, 0, 0, 0);
      acc11 = MFMA(e1y, bB1, acc11, 0, 0, 0);
      acc2  = MFMA(expand_byte(cA2, lgsh), bM, acc2, 0, 0, 0);
    }
    // ---- odd phase: compute kt+1 from bt[1], masks B ----
    __syncthreads();                       // drains stage(kt+1 -> bt[1])
    if (kt + 2 < 64) {                     // stage kt+2 -> bt[0]
      const u16* hp = H + (size_t)(kt + 2) * 73728;
      GLOAD16(hp + soff0, (char*)&bt[0][0] + (size_t)e0 * 2);
      GLOAD16(hp + soff1, (char*)&bt[0][0] + (size_t)e1 * 2);
      if (tid < 128)
        GLOAD16(hp + soff2, (char*)&bt[0][0] + (size_t)e2 * 2);
      const size_t mo = (size_t)(kt + 2) * 4096;
      cA0 = mp1a[mo]; cA1 = mp1b[mo]; cA2 = mp2[(size_t)(kt + 2) * 8192];
    }
    {
      const u16* src = &bt[1][0];
      short8 e0x = expand_byte(cB0.x, lgsh), e0y = expand_byte(cB0.y, lgsh);
      short8 e1x = expand_byte(cB1.x, lgsh), e1y = expand_byte(cB1.y, lgsh);
      short8 bA0 = *(const short8*)(src + fA0);
      short8 bA1 = *(const short8*)(src + fA1);
      short8 bB0 = *(const short8*)(src + fB0);
      short8 bB1 = *(const short8*)(src + fB1);
      short8 bM  = *(const short8*)(src + fM);
      acc00 = MFMA(e0x, bA0, acc00, 0, 0, 0);
      acc01 = MFMA(e0x, bA1, acc01, 0, 0, 0);
      acc00 = MFMA(e0y, bB0, acc00, 0, 0, 0);
      acc01 = MFMA(e0y, bB1, acc01, 0, 0, 0);
      acc10 = MFMA(e1x, bA0, acc10, 0, 0, 0);
      acc11 = MFMA(e1x, bA1, acc11, 0, 0, 0);
      acc10 = MFMA(e1y, bB0, acc10, 0, 0, 0);
      acc11 = MFMA(e1y, bB1, acc11, 0, 0, 0);
      acc2  = MFMA(expand_byte(cB2, lgsh), bM, acc2, 0, 0, 0);
    }
  }

  // epilogue: combine m2 kf-partials -> f2 bf16 tile
#pragma unroll
  for (int gg = 0; gg < 4; ++gg)
    f2pf[kf2][fm2 * 16 + lg * 4 + gg][lr] = acc2[gg];
  __syncthreads();
#pragma unroll
  for (int j = 0; j < 2; ++j) {
    int e = j * 512 + tid;                 // 64x16 = 1024 elems
    int row = e >> 4, col = e & 15;
    f2s[row * 40 + col] = f2bf(f2pf[0][row][col] + f2pf[1][row][col]);
    f2s[row * 40 + 16 + col] = 0;          // zero-pad cols 16..31
  }
  __syncthreads();

  // epilogue MFMA: acc[i][fj] += f2frag(fm=2g+i) x Wb2frag(fn=2c+fj)
  short8 bw0 = *(const short8*)(wb2s + ((lg * 128) + (c * 2 + 0) * 16 + lr) * 8);
  short8 bw1 = *(const short8*)(wb2s + ((lg * 128) + (c * 2 + 1) * 16 + lr) * 8);
  {
    short8 af0 = *(const short8*)(f2s + ((g * 2 + 0) * 16 + lr) * 40 + lg * 8);
    short8 af1 = *(const short8*)(f2s + ((g * 2 + 1) * 16 + lr) * 40 + lg * 8);
    acc00 = MFMA(af0, bw0, acc00, 0, 0, 0);
    acc01 = MFMA(af0, bw1, acc01, 0, 0, 0);
    acc10 = MFMA(af1, bw0, acc10, 0, 0, 0);
    acc11 = MFMA(af1, bw1, acc11, 0, 0, 0);
  }

  // final: + rs1*q1 + rs2*q2 + bb, store f32
  const int col0 = (c * 2 + 0) * 16 + lr, col1 = (c * 2 + 1) * 16 + lr;
  const float q10 = q1[col0], q20 = q2[col0], bb0 = bb[col0];
  const float q11 = q1[col1], q21 = q2[col1], bb1 = bb[col1];
#pragma unroll
  for (int i = 0; i < 2; ++i) {
    f32x4 a0 = i ? acc10 : acc00;
    f32x4 a1 = i ? acc11 : acc01;
#pragma unroll
    for (int gg = 0; gg < 4; ++gg) {
      int row = (g * 2 + i) * 16 + lg * 4 + gg;
      float r1 = rs1[i0 + row], r2 = rs2[i0 + row];
      size_t obase = ((size_t)b * 4096 + i0 + row) * 128;
      out[obase + col0] = a0[gg] + r1 * q10 + r2 * q20 + bb0;
      out[obase + col1] = a1[gg] + r1 * q11 + r2 * q21 + bb1;
    }
  }
}

extern "C" void kernel_launch(void* const* d_in, const int* in_sizes, int n_in,
                              void* d_out, int out_size, void* d_ws, size_t ws_size,
                              hipStream_t stream) {
  const float* x  = (const float*)d_in[0];
  const int*   sp = (const int*)d_in[1];
  const float* W1 = (const float*)d_in[2];
  const float* b1 = (const float*)d_in[3];
  const float* W2 = (const float*)d_in[4];
  const float* b2 = (const float*)d_in[5];
  const float* Wb = (const float*)d_in[6];
  const float* bb = (const float*)d_in[7];
  float* out = (float*)d_out;
  char* ws = (char*)d_ws;

  u16* H = (u16*)(ws + WS_H);
  float* P1 = (float*)(ws + WS_P1);
  float* q1 = (float*)(ws + WS_Q1);
  float* q2 = (float*)(ws + WS_Q2);
  unsigned long long* m1p = (unsigned long long*)(ws + WS_M1P);
  unsigned long long* m2p = (unsigned long long*)(ws + WS_M2P);
  float* rs1 = (float*)(ws + WS_RS1);
  float* rs2 = (float*)(ws + WS_RS2);

  kmask<<<1024, 256, 0, stream>>>(sp, m1p, m2p, rs1, rs2);
  kprep<<<64, 256, 0, stream>>>(W1, Wb, b1, b2, P1, q1, q2);
  kproj<<<512, 256, 0, stream>>>(x, P1, W2, H);
  kb1<<<512, 512, 0, stream>>>(H, (const uint2*)m1p, (const uint32_t*)m2p,
                               rs1, rs2, q1, q2, Wb, bb, out);
}

// Round 9
// 92.434 us; speedup vs baseline: 52.3170x; 1.2237x over previous
//
#include <hip/hip_runtime.h>
#include <stdint.h>

typedef unsigned short u16;
typedef __attribute__((ext_vector_type(8))) short short8;
typedef __attribute__((ext_vector_type(4))) float f32x4;

#define MFMA __builtin_amdgcn_mfma_f32_16x16x32_bf16

__device__ __forceinline__ u16 f2bf(float f) {
  union { float f; uint32_t u; } v; v.f = f;
  return (u16)((v.u + 0x7FFFu + ((v.u >> 16) & 1u)) >> 16);
}

#define GLOAD16(gp, lp) \
  __builtin_amdgcn_global_load_lds((const __attribute__((address_space(1))) uint32_t*)(gp), \
                                   (__attribute__((address_space(3))) uint32_t*)(lp), 16, 0, 0)

// ws layout (bytes)
#define WS_H    0          // u16 H[64][2][8][9][64][8]  fragment-major (9,437,184 B)
#define WS_Q1   9502720    // f32 q1[128]
#define WS_Q2   9503232    // f32 q2[128]
#define WS_M1P  9503744    // u64 m1p[64][4096]   (TRANSPOSED: [kt][row])
#define WS_M2P  11600896   // u64 m2p[64][4096]
#define WS_RS1  13698048   // f32 rs1[4096]
#define WS_RS2  13714432   // f32 rs2[4096]
#define WS_WSB  13730816   // u16 wsb[16][144][8] blocked B operand (36,864 B)

// ---------------- kernel 0: fused kmask (blocks 0-1023) + kprep (blocks 1024-1087) ----------------
__global__ __launch_bounds__(256) void k0(const int* __restrict__ sp,
                                          unsigned long long* __restrict__ m1p,
                                          unsigned long long* __restrict__ m2p,
                                          float* __restrict__ rs1, float* __restrict__ rs2,
                                          const float* __restrict__ W1, const float* __restrict__ Wb,
                                          const float* __restrict__ b1, const float* __restrict__ b2,
                                          const float* __restrict__ W2,
                                          float* __restrict__ q1, float* __restrict__ q2,
                                          u16* __restrict__ wsbg) {
  const int tid = threadIdx.x;
  if (blockIdx.x < 1024) {
    // ---- kmask: pack masks into bits (transposed [kt][row]) + row sums ----
    int wave = tid >> 6, lane = tid & 63;
    int i = blockIdx.x * 4 + wave;
    const int* rowp = sp + (size_t)i * 4096;
    int c1 = 0, c2 = 0;
    for (int w = 0; w < 64; ++w) {
      int v = rowp[w * 64 + lane];
      unsigned long long bb1 = __ballot(v <= 1);
      unsigned long long bb2 = __ballot(v == 2);
      if (lane == 0) {
        m1p[(size_t)w * 4096 + i] = bb1;
        m2p[(size_t)w * 4096 + i] = bb2;
        c1 += __popcll(bb1);
        c2 += __popcll(bb2);
      }
    }
    if (lane == 0) { rs1[i] = (float)c1; rs2[i] = (float)c2; }
    return;
  }
  // ---- kprep: wsbg = blocked bf16 [W1@Wb1 | W2]; q1 = b1@Wb1; q2 = b2@Wb2 ----
  int idx = (int)(blockIdx.x - 1024) * 256 + tid;   // 0..16383
  int a = idx >> 7, c = idx & 127;
  float acc = 0.f;
  for (int k = 0; k < 128; ++k) acc += W1[a * 128 + k] * Wb[k * 128 + c];
  wsbg[(((a >> 3) * 144) + c) * 8 + (a & 7)] = f2bf(acc);
  if (idx < 2048) {
    int k = idx >> 4, nn2 = idx & 15;
    wsbg[(((k >> 3) * 144) + 128 + nn2) * 8 + (k & 7)] = f2bf(W2[k * 16 + nn2]);
  }
  if (idx < 128) {
    float s1 = 0.f, s2 = 0.f;
    for (int k = 0; k < 128; ++k) s1 += b1[k] * Wb[k * 128 + idx];
    for (int k = 0; k < 16; ++k)  s2 += b2[k] * Wb[(128 + k) * 128 + idx];
    q1[idx] = s1; q2[idx] = s2;
  }
}

// ---------------- kernel A': u1h2 -> fragment-major H ----------------
// grid 256, 512 threads; block handles 128 rows (2 kt-slabs of one batch b).
__global__ __launch_bounds__(512, 1) void kproj(const float* __restrict__ x,
                                                const u16* __restrict__ wsbg,
                                                u16* __restrict__ H) {
  __shared__ u16 wsb[18432];              // blocked B operand (36 KB)
  __shared__ u16 xs[128 * 136];           // x rows bf16 (34.8 KB)
  __shared__ u16 hs[128 * 146];           // result staging (37.4 KB)
  const int tid = threadIdx.x;
  const int bid = blockIdx.x;
  const int r0 = bid * 128;
  const int b = bid >> 5;
  const int kt0 = (bid & 31) * 2;

  // stage blocked B via global_load_lds (36864 B)
  {
    const int e0 = tid * 8;
    GLOAD16(wsbg + e0,         (char*)&wsb[0] + e0 * 2);
    GLOAD16(wsbg + 4096 + e0,  (char*)&wsb[0] + (4096 + e0) * 2);
    GLOAD16(wsbg + 8192 + e0,  (char*)&wsb[0] + (8192 + e0) * 2);
    GLOAD16(wsbg + 12288 + e0, (char*)&wsb[0] + (12288 + e0) * 2);
    if (tid < 256)
      GLOAD16(wsbg + 16384 + e0, (char*)&wsb[0] + (16384 + e0) * 2);
  }
  // stage x rows -> xs[128][136] bf16
  {
    const float* xp = x + ((size_t)(r0 + (tid >> 2))) * 128 + (tid & 3) * 32;
    u16* xd = xs + (tid >> 2) * 136 + (tid & 3) * 32;
#pragma unroll
    for (int i = 0; i < 4; ++i) {
      f32x4 a = ((const f32x4*)xp)[i * 2];
      f32x4 bq = ((const f32x4*)xp)[i * 2 + 1];
      short8 pk;
      pk[0] = (short)f2bf(a[0]); pk[1] = (short)f2bf(a[1]);
      pk[2] = (short)f2bf(a[2]); pk[3] = (short)f2bf(a[3]);
      pk[4] = (short)f2bf(bq[0]); pk[5] = (short)f2bf(bq[1]);
      pk[6] = (short)f2bf(bq[2]); pk[7] = (short)f2bf(bq[3]);
      *(short8*)(xd + i * 8) = pk;
    }
  }
  __syncthreads();

  const int w = tid >> 6, l = tid & 63, lr = l & 15, lg = l >> 4;
  f32x4 acc[9];
  f32x4 zz = {0.f, 0.f, 0.f, 0.f};
#pragma unroll
  for (int fn = 0; fn < 9; ++fn) acc[fn] = zz;
#pragma unroll
  for (int kf = 0; kf < 4; ++kf) {
    short8 af = *(const short8*)(xs + (w * 16 + lr) * 136 + kf * 32 + lg * 8);
#pragma unroll
    for (int fn = 0; fn < 9; ++fn) {
      short8 bf = *(const short8*)(wsb + (((kf * 4 + lg) * 144) + fn * 16 + lr) * 8);
      acc[fn] = MFMA(af, bf, acc[fn], 0, 0, 0);
    }
  }
  __syncthreads();
#pragma unroll
  for (int fn = 0; fn < 9; ++fn)
#pragma unroll
    for (int g = 0; g < 4; ++g)
      hs[(w * 16 + lg * 4 + g) * 146 + fn * 16 + lr] = f2bf(acc[fn][g]);
  __syncthreads();
  // fragment-major coalesced write to H (2 kt-slabs)
  for (int i = 0; i < 5; ++i) {
    int e = i * 512 + tid;
    if (e < 2304) {
      int slab = e / 1152, rem = e % 1152;
      int jbl = rem / 144, n = rem % 144;
      union { u16 s[8]; uint4 v; } pk;
#pragma unroll
      for (int r = 0; r < 8; ++r) pk.s[r] = hs[(slab * 64 + jbl * 8 + r) * 146 + n];
      int kf = jbl >> 2, lgw = jbl & 3, fn = n >> 4, lrw = n & 15;
      size_t di = ((((size_t)(kt0 + slab) * 2 + kf) * 8 + b) * 9 + fn) * 512 + (lgw * 16 + lrw) * 8;
      *(uint4*)(H + di) = pk.v;
    }
  }
}

// expand 8 mask bits (byte lgsh/8 of a 32-bit half-word) -> 8 bf16 {0,1} packed as short8
__device__ __forceinline__ short8 expand_byte(uint32_t wd, int lgsh) {
  uint32_t b = (wd >> lgsh) & 0xFFu;
  uint32_t t = b * 0x8001u;
  union { uint32_t u[4]; short8 s; } r;
  r.u[0] = (t & 0x00010001u) * 0x3F80u;
  r.u[1] = (t & 0x00040004u) * 0x0FE0u;
  r.u[2] = (t & 0x00100010u) * 0x03F8u;
  r.u[3] = (t & 0x00400040u) * 0x00FEu;
  return r.s;
}

// ---------------- kernel B1: counted-vmcnt 3-buffer pipeline ----------------
// grid 512 (b=bid&7, 64-row panels) -> 2 blocks/CU. Per phase: vmcnt(S) [stage(p+1) stays
// in flight across barrier], raw s_barrier, issue stage(p+2), setprio-wrapped 9 MFMA.
// Masks staged to LDS via global_load_lds (wave 0 carries them) -> loop has no vmcnt register loads.
__global__ __launch_bounds__(512, 4) void kb1(const u16* __restrict__ H,
                                              const char* __restrict__ M1b,
                                              const char* __restrict__ M2b,
                                              const float* __restrict__ rs1, const float* __restrict__ rs2,
                                              const float* __restrict__ q1, const float* __restrict__ q2,
                                              const float* __restrict__ Wb, const float* __restrict__ bb,
                                              float* __restrict__ out) {
  __shared__ u16 bt[3][9216];              // 3-buffered B tile (54 KB)
  __shared__ u16 mkb[3][512];              // 3-buffered mask slab (3 KB): 512B m1 rows + 512B m2 rows
  __shared__ float f2pf[2][64][16];        // m2@h2 kf-partials (8 KB)
  __shared__ u16 f2s[64 * 40];             // f2 bf16, K padded to 32 (5 KB)
  __shared__ u16 wb2s[4096];               // Wb2 padded to K=32 (8 KB)   -> total 79.9 KB

  const int tid = threadIdx.x;
  const int bid = blockIdx.x;
  const int b = bid & 7;
  const int i0 = (bid >> 3) * 64;

  const int w = tid >> 6, l = tid & 63, lr = l & 15, lg = l >> 4;
  const int g = w >> 2, c = w & 3;
  const int fm2 = w & 3, kf2 = w >> 2;
  const int lgsh = lg * 8;

  // stage source offsets (u16 units within a kt-slab, b folded in)
  const int e0 = tid * 8, e1 = 4096 + tid * 8, e2 = 8192 + tid * 8;
  const uint32_t soff0 = b * 4608 + e0;
  const uint32_t soff1 = b * 4608 + (uint32_t)(e1 < 4608 ? e1 : 32256 + e1);
  const uint32_t soff2 = b * 4608 + 32256 + e2;
  const char* mksrc = ((tid < 32) ? M1b : M2b) + (size_t)i0 * 8 + (size_t)(tid & 31) * 16;

#define STAGE(P, BUF) { \
    const u16* hp_ = H + (size_t)(P) * 73728; \
    GLOAD16(hp_ + soff0, (char*)&bt[BUF][0] + e0 * 2); \
    GLOAD16(hp_ + soff1, (char*)&bt[BUF][0] + e1 * 2); \
    if (tid < 128) GLOAD16(hp_ + soff2, (char*)&bt[BUF][0] + e2 * 2); \
    if (tid < 64)  GLOAD16(mksrc + (size_t)(P) * 32768, (char*)&mkb[BUF][0] + tid * 16); }

  // compute-phase LDS fragment offsets (u16)
  const int fA0 = (c * 2 + 0) * 512 + l * 8;
  const int fA1 = (c * 2 + 1) * 512 + l * 8;
  const int fB0 = 4608 + fA0;
  const int fB1 = 4608 + fA1;
  const int fM  = kf2 * 4608 + 8 * 512 + l * 8;

  f32x4 zz = {0.f, 0.f, 0.f, 0.f};
  f32x4 acc00 = zz, acc01 = zz, acc10 = zz, acc11 = zz;
  f32x4 acc2 = zz;

#define WAITV { if (w == 0) asm volatile("s_waitcnt vmcnt(4)" ::: "memory"); \
                else if (w == 1) asm volatile("s_waitcnt vmcnt(3)" ::: "memory"); \
                else asm volatile("s_waitcnt vmcnt(2)" ::: "memory"); }

#define COMPUTE(BUF) { \
    const u16* src_ = &bt[BUF][0]; \
    uint2 c0_ = *(const uint2*)&mkb[BUF][((g * 2 + 0) * 16 + lr) * 4]; \
    uint2 c1_ = *(const uint2*)&mkb[BUF][((g * 2 + 1) * 16 + lr) * 4]; \
    uint32_t c2_ = *(const uint32_t*)&mkb[BUF][256 + (fm2 * 16 + lr) * 4 + kf2 * 2]; \
    short8 bA0_ = *(const short8*)(src_ + fA0); \
    short8 bA1_ = *(const short8*)(src_ + fA1); \
    short8 bB0_ = *(const short8*)(src_ + fB0); \
    short8 bB1_ = *(const short8*)(src_ + fB1); \
    short8 bM_  = *(const short8*)(src_ + fM); \
    short8 e0x_ = expand_byte(c0_.x, lgsh), e0y_ = expand_byte(c0_.y, lgsh); \
    short8 e1x_ = expand_byte(c1_.x, lgsh), e1y_ = expand_byte(c1_.y, lgsh); \
    short8 e2v_ = expand_byte(c2_, lgsh); \
    __builtin_amdgcn_s_setprio(1); \
    acc00 = MFMA(e0x_, bA0_, acc00, 0, 0, 0); \
    acc01 = MFMA(e0x_, bA1_, acc01, 0, 0, 0); \
    acc00 = MFMA(e0y_, bB0_, acc00, 0, 0, 0); \
    acc01 = MFMA(e0y_, bB1_, acc01, 0, 0, 0); \
    acc10 = MFMA(e1x_, bA0_, acc10, 0, 0, 0); \
    acc11 = MFMA(e1x_, bA1_, acc11, 0, 0, 0); \
    acc10 = MFMA(e1y_, bB0_, acc10, 0, 0, 0); \
    acc11 = MFMA(e1y_, bB1_, acc11, 0, 0, 0); \
    acc2  = MFMA(e2v_, bM_, acc2, 0, 0, 0); \
    __builtin_amdgcn_s_setprio(0); }

#define PHASE(P, BUF, BUF2) { WAITV; __builtin_amdgcn_s_barrier(); \
    STAGE((P) + 2, BUF2); COMPUTE(BUF) }

  // prologue: stage kt=0,1
  STAGE(0, 0);
  STAGE(1, 1);

  // stage Wb2 (VALU work overlaps prologue load latency)
#pragma unroll
  for (int i = 0; i < 8; ++i) {
    int e = i * 512 + tid;
    int r_ = e & 7, nn = (e >> 3) & 127, jb = e >> 10;
    int k = jb * 8 + r_;
    wb2s[e] = f2bf((k < 16) ? Wb[(128 + k) * 128 + nn] : 0.f);
  }

  for (int p = 0; p < 60; p += 3) {
    PHASE(p, 0, 2);
    PHASE(p + 1, 1, 0);
    PHASE(p + 2, 2, 1);
  }
  PHASE(60, 0, 2);
  PHASE(61, 1, 0);
  { WAITV; __builtin_amdgcn_s_barrier(); COMPUTE(2) }                          // phase 62
  { asm volatile("s_waitcnt vmcnt(0)" ::: "memory");
    __builtin_amdgcn_s_barrier(); COMPUTE(0) }                                 // phase 63

  // epilogue: combine m2 kf-partials -> f2 bf16 tile
#pragma unroll
  for (int gg = 0; gg < 4; ++gg)
    f2pf[kf2][fm2 * 16 + lg * 4 + gg][lr] = acc2[gg];
  __syncthreads();
#pragma unroll
  for (int j = 0; j < 2; ++j) {
    int e = j * 512 + tid;
    int row = e >> 4, col = e & 15;
    f2s[row * 40 + col] = f2bf(f2pf[0][row][col] + f2pf[1][row][col]);
    f2s[row * 40 + 16 + col] = 0;
  }
  __syncthreads();

  // epilogue MFMA: acc[i][fj] += f2frag(fm=2g+i) x Wb2frag(fn=2c+fj)
  short8 bw0 = *(const short8*)(wb2s + ((lg * 128) + (c * 2 + 0) * 16 + lr) * 8);
  short8 bw1 = *(const short8*)(wb2s + ((lg * 128) + (c * 2 + 1) * 16 + lr) * 8);
  {
    short8 af0 = *(const short8*)(f2s + ((g * 2 + 0) * 16 + lr) * 40 + lg * 8);
    short8 af1 = *(const short8*)(f2s + ((g * 2 + 1) * 16 + lr) * 40 + lg * 8);
    acc00 = MFMA(af0, bw0, acc00, 0, 0, 0);
    acc01 = MFMA(af0, bw1, acc01, 0, 0, 0);
    acc10 = MFMA(af1, bw0, acc10, 0, 0, 0);
    acc11 = MFMA(af1, bw1, acc11, 0, 0, 0);
  }

  // final: + rs1*q1 + rs2*q2 + bb, store f32
  const int col0 = (c * 2 + 0) * 16 + lr, col1 = (c * 2 + 1) * 16 + lr;
  const float q10 = q1[col0], q20 = q2[col0], bb0 = bb[col0];
  const float q11 = q1[col1], q21 = q2[col1], bb1 = bb[col1];
#pragma unroll
  for (int i = 0; i < 2; ++i) {
    f32x4 a0 = i ? acc10 : acc00;
    f32x4 a1 = i ? acc11 : acc01;
#pragma unroll
    for (int gg = 0; gg < 4; ++gg) {
      int row = (g * 2 + i) * 16 + lg * 4 + gg;
      float r1 = rs1[i0 + row], r2 = rs2[i0 + row];
      size_t obase = ((size_t)b * 4096 + i0 + row) * 128;
      out[obase + col0] = a0[gg] + r1 * q10 + r2 * q20 + bb0;
      out[obase + col1] = a1[gg] + r1 * q11 + r2 * q21 + bb1;
    }
  }
}

extern "C" void kernel_launch(void* const* d_in, const int* in_sizes, int n_in,
                              void* d_out, int out_size, void* d_ws, size_t ws_size,
                              hipStream_t stream) {
  const float* x  = (const float*)d_in[0];
  const int*   sp = (const int*)d_in[1];
  const float* W1 = (const float*)d_in[2];
  const float* b1 = (const float*)d_in[3];
  const float* W2 = (const float*)d_in[4];
  const float* b2 = (const float*)d_in[5];
  const float* Wb = (const float*)d_in[6];
  const float* bb = (const float*)d_in[7];
  float* out = (float*)d_out;
  char* ws = (char*)d_ws;

  u16* H = (u16*)(ws + WS_H);
  float* q1 = (float*)(ws + WS_Q1);
  float* q2 = (float*)(ws + WS_Q2);
  unsigned long long* m1p = (unsigned long long*)(ws + WS_M1P);
  unsigned long long* m2p = (unsigned long long*)(ws + WS_M2P);
  float* rs1 = (float*)(ws + WS_RS1);
  float* rs2 = (float*)(ws + WS_RS2);
  u16* wsbg = (u16*)(ws + WS_WSB);

  k0<<<1088, 256, 0, stream>>>(sp, m1p, m2p, rs1, rs2, W1, Wb, b1, b2, W2, q1, q2, wsbg);
  kproj<<<256, 512, 0, stream>>>(x, wsbg, H);
  kb1<<<512, 512, 0, stream>>>(H, (const char*)m1p, (const char*)m2p,
                               rs1, rs2, q1, q2, Wb, bb, out);
}